// Round 1
// 1068.975 us; speedup vs baseline: 1.3912x; 1.3912x over previous
//
#include <hip/hip_runtime.h>

typedef unsigned short u16;
typedef __bf16 v8bf __attribute__((ext_vector_type(8)));
typedef float  v4f  __attribute__((ext_vector_type(4)));

__device__ __forceinline__ float b2f(u16 h) { return __uint_as_float(((unsigned)h) << 16); }
__device__ __forceinline__ u16 f2b(float f) {
    unsigned u = __float_as_uint(f);
    unsigned r = (u + 0x7FFFu + ((u >> 16) & 1u)) >> 16;  // RNE
    return (u16)r;
}

// ---------------------------------------------------------------------------
// fp32 -> bf16 bulk conversion; 4 independent tensors per launch (blockIdx.y
// selects). 8 elements/thread, float4 loads / ushort4 stores.
__global__ __launch_bounds__(256) void cvt4_kernel(
    const float* __restrict__ s0, u16* __restrict__ d0, int n0,
    const float* __restrict__ s1, u16* __restrict__ d1, int n1,
    const float* __restrict__ s2, u16* __restrict__ d2, int n2,
    const float* __restrict__ s3, u16* __restrict__ d3, int n3) {
    const float* s; u16* d; int n;
    switch (blockIdx.y) {
        case 0:  s = s0; d = d0; n = n0; break;
        case 1:  s = s1; d = d1; n = n1; break;
        case 2:  s = s2; d = d2; n = n2; break;
        default: s = s3; d = d3; n = n3; break;
    }
    int i = blockIdx.x * 256 + threadIdx.x;   // handles elements [8i, 8i+8)
    if (i * 8 < n) {
        float4 a = ((const float4*)s)[i * 2];
        float4 b = ((const float4*)s)[i * 2 + 1];
        ((ushort4*)d)[i * 2]     = make_ushort4(f2b(a.x), f2b(a.y), f2b(a.z), f2b(a.w));
        ((ushort4*)d)[i * 2 + 1] = make_ushort4(f2b(b.x), f2b(b.y), f2b(b.z), f2b(b.w));
    }
}

// ---------------------------------------------------------------------------
// mod3[p][b][j] = sum_k cond[b][k]*mw_p[j][k] + mb_p[j]   (p<3, b<8, j<3072)
__global__ __launch_bounds__(256) void mod_kernel(
    const float* __restrict__ cond,
    const float* __restrict__ mw0, const float* __restrict__ mb0,
    const float* __restrict__ mw1, const float* __restrict__ mb1,
    const float* __restrict__ mw2, const float* __restrict__ mb2,
    float* __restrict__ mod3) {
    const int tid = threadIdx.x, wave = tid >> 6, lane = tid & 63;
    int job = blockIdx.x * 4 + wave;  // 73728 jobs
    int p = job / 24576, r = job % 24576;
    int b = r / 3072, j = r % 3072;
    const float* mw = p == 0 ? mw0 : (p == 1 ? mw1 : mw2);
    const float* mb = p == 0 ? mb0 : (p == 1 ? mb1 : mb2);
    const float4* c = (const float4*)(cond + b * 1024);
    const float4* wr = (const float4*)(mw + (size_t)j * 1024);
    float s = 0.f;
#pragma unroll
    for (int t = 0; t < 4; t++) {
        float4 cv = c[lane + t * 64], wv = wr[lane + t * 64];
        s += cv.x * wv.x + cv.y * wv.y + cv.z * wv.z + cv.w * wv.w;
    }
#pragma unroll
    for (int o = 32; o > 0; o >>= 1) s += __shfl_xor(s, o, 64);
    if (lane == 0) mod3[(size_t)p * 24576 + b * 3072 + j] = s + mb[j];
}

// ---------------------------------------------------------------------------
// AdaRMS: bf16 out = x*rsqrt(mean(x^2)+eps)*w*(1+scale)+shift  (fp32 x,w,mod)
__global__ __launch_bounds__(256) void adarms_kernel(
    const float* __restrict__ Xf, const float* __restrict__ w,
    const float* __restrict__ mod, u16* __restrict__ Out) {
    __shared__ float red[4];
    const int row = blockIdx.x, tid = threadIdx.x;
    const int bidx = row >> 9;
    const float* x = Xf + (size_t)row * 1024;
    float4 v = *(const float4*)(x + tid * 4);
    float s = v.x * v.x + v.y * v.y + v.z * v.z + v.w * v.w;
#pragma unroll
    for (int o = 32; o > 0; o >>= 1) s += __shfl_xor(s, o, 64);
    if ((tid & 63) == 0) red[tid >> 6] = s;
    __syncthreads();
    float tot = red[0] + red[1] + red[2] + red[3];
    float norm = 1.0f / sqrtf(tot * (1.f / 1024.f) + 1e-6f);
    const float* mo = mod + (size_t)bidx * 3072;
    int d = tid * 4;
    float4 wv = *(const float4*)(w + d);
    const float xv[4] = {v.x, v.y, v.z, v.w};
    const float wa[4] = {wv.x, wv.y, wv.z, wv.w};
    u16 o4[4];
#pragma unroll
    for (int t = 0; t < 4; t++) {
        float sc = mo[d + t], sh = mo[1024 + d + t];
        o4[t] = f2b(xv[t] * norm * wa[t] * (1.f + sc) + sh);
    }
    *(ushort4*)(Out + (size_t)row * 1024 + d) = make_ushort4(o4[0], o4[1], o4[2], o4[3]);
}

// ---------------------------------------------------------------------------
// Staging 128 rows x 32 k into LDS as bf16 (GEMM).
template <typename T>
__device__ __forceinline__ void stage_tile(const T* __restrict__ G, int ldg, int row0,
                                           int k0, u16* lds, int tid) {
    if constexpr (sizeof(T) == 2) {
        const int wave = tid >> 6, lane = tid & 63;
        const int r4 = lane >> 2, c8 = (lane & 3) * 8;
#pragma unroll
        for (int i = 0; i < 2; i++) {
            int row = wave * 32 + i * 16;
            __builtin_amdgcn_global_load_lds(
                (__attribute__((address_space(1))) void*)((const u16*)G + (size_t)(row0 + row + r4) * ldg + k0 + c8),
                (__attribute__((address_space(3))) void*)(&lds[row * 32]), 16, 0, 0);
        }
    } else {
        const int row = tid >> 1, col = (tid & 1) * 16;
        const float* src = (const float*)G + (size_t)(row0 + row) * ldg + k0 + col;
        float4 f0 = *(const float4*)(src);
        float4 f1 = *(const float4*)(src + 4);
        float4 f2 = *(const float4*)(src + 8);
        float4 f3 = *(const float4*)(src + 12);
        ushort4* dst = (ushort4*)(&lds[row * 32 + col]);
        dst[0] = make_ushort4(f2b(f0.x), f2b(f0.y), f2b(f0.z), f2b(f0.w));
        dst[1] = make_ushort4(f2b(f1.x), f2b(f1.y), f2b(f1.z), f2b(f1.w));
        dst[2] = make_ushort4(f2b(f2.x), f2b(f2.y), f2b(f2.z), f2b(f2.w));
        dst[3] = make_ushort4(f2b(f3.x), f2b(f3.y), f2b(f3.z), f2b(f3.w));
    }
}

// ---------------------------------------------------------------------------
// GEMM: C(M,N) = A(M,K) @ Bw(N,K)^T, 128x128 tile, BK=32, mfma 16x16x32 bf16.
// MODE 0: Cb[idx] = bf16(acc)
// MODE 1: Xf[row*1024+col] += gate[b][col]*acc
// MODE 2: Cb[idx] = bf16(silu(Cb[idx])*acc)
// MODE 3: Cf[idx] = Xf[row*1024+col] + gate*acc   (fp32 final output)
template <typename TA, typename TB, int MODE>
__global__ __launch_bounds__(256) void gemm_bt(
    const TA* __restrict__ A, const TB* __restrict__ Bw,
    u16* __restrict__ Cb, float* __restrict__ Cf,
    float* __restrict__ Xf, const float* __restrict__ mod,
    int M, int N, int K, int ldc, int coff) {
    __shared__ u16 As[128 * 32];
    __shared__ u16 Bs[128 * 32];
    const int tid = threadIdx.x;
    const int wave = tid >> 6, lane = tid & 63;
    const int m0 = blockIdx.y * 128, n0 = blockIdx.x * 128;
    const int wm = (wave >> 1) * 64, wn = (wave & 1) * 64;
    const int kq = lane >> 4, rr = lane & 15;

    v4f acc[4][4];
#pragma unroll
    for (int i = 0; i < 4; i++)
#pragma unroll
        for (int j = 0; j < 4; j++) acc[i][j] = (v4f){0.f, 0.f, 0.f, 0.f};

    for (int k0 = 0; k0 < K; k0 += 32) {
        __syncthreads();
        stage_tile<TA>(A, K, m0, k0, As, tid);
        stage_tile<TB>(Bw, K, n0, k0, Bs, tid);
        __syncthreads();
        v8bf a[4], b[4];
#pragma unroll
        for (int i = 0; i < 4; i++) a[i] = *(const v8bf*)(&As[(wm + i * 16 + rr) * 32 + kq * 8]);
#pragma unroll
        for (int j = 0; j < 4; j++) b[j] = *(const v8bf*)(&Bs[(wn + j * 16 + rr) * 32 + kq * 8]);
#pragma unroll
        for (int i = 0; i < 4; i++)
#pragma unroll
            for (int j = 0; j < 4; j++)
                acc[i][j] = __builtin_amdgcn_mfma_f32_16x16x32_bf16(a[i], b[j], acc[i][j], 0, 0, 0);
    }

    const int quad = lane >> 4, cl = lane & 15;
#pragma unroll
    for (int i = 0; i < 4; i++)
#pragma unroll
        for (int j = 0; j < 4; j++)
#pragma unroll
            for (int r = 0; r < 4; r++) {
                int row = m0 + wm + i * 16 + quad * 4 + r;
                int col = n0 + wn + j * 16 + cl;
                size_t idx = (size_t)row * ldc + coff + col;
                float v = acc[i][j][r];
                if constexpr (MODE == 0) {
                    Cb[idx] = f2b(v);
                } else if constexpr (MODE == 1) {
                    float g = mod[(row >> 9) * 3072 + 2048 + col];
                    Xf[(size_t)row * 1024 + col] += g * v;
                } else if constexpr (MODE == 2) {
                    float gv = b2f(Cb[idx]);
                    float s = gv / (1.f + __expf(-gv));
                    Cb[idx] = f2b(s * v);
                } else {
                    float g = mod[(row >> 9) * 3072 + 2048 + col];
                    Cf[idx] = Xf[(size_t)row * 1024 + col] + g * v;
                }
            }
}

// ---------------------------------------------------------------------------
// MFMA flash attention. Block = 4 waves; wave w handles 16 queries, one head.
// grid (Nq/64, H, B). S^T = K·Q^T  (C layout: col=q=lane&15, row=kv) so softmax
// stats live per lane&15; O^T = V^T·P^T has the same col=q layout -> alpha
// rescale is lane-local. P routes through per-wave LDS (m120 pattern).
// Ks/Qs use XOR-chunk swizzle (chunk ^= row&7) so b128 frag reads are ~2-way.
// Vs padded to 66 (33-dword stride) so per-lane column reads are conflict-free.
#define ATTN_SCL 0.125f
__global__ __launch_bounds__(256) void attn_kernel(
    const u16* __restrict__ Q, int ldq,
    const u16* __restrict__ Kp, const u16* __restrict__ Vp, int ldkv,
    u16* __restrict__ Out, int S) {
    __shared__ u16 Ks[64 * 64];
    __shared__ u16 Qs[64 * 64];
    __shared__ u16 Vs[64 * 66];
    __shared__ u16 Ps[4][16 * 72];
    const int tid = threadIdx.x, wave = tid >> 6, lane = tid & 63;
    const int b = blockIdx.z, h = blockIdx.y, q0 = blockIdx.x * 64;
    const int Nq = 512;
    const int rr = lane & 15, quad = lane >> 4;
    const int drow = lane >> 3;                  // 0..7 within a 1KB DMA issue
    const int dchunk = (lane & 7) ^ drow;        // swizzled global 16B chunk

    // ---- stage Q tile (64 q x 64 d), swizzled ----
#pragma unroll
    for (int i = 0; i < 2; i++) {
        int r = wave * 16 + i * 8 + drow;
        __builtin_amdgcn_global_load_lds(
            (__attribute__((address_space(1))) void*)(Q + (size_t)(b * Nq + q0 + r) * ldq + h * 64 + dchunk * 8),
            (__attribute__((address_space(3))) void*)(&Qs[(wave * 16 + i * 8) * 64]), 16, 0, 0);
    }
    __syncthreads();  // drains vmcnt: Qs visible

    // hoist Q B-fragments (row = wave*16+rr, k-halves)
    v8bf qf[2];
#pragma unroll
    for (int h2 = 0; h2 < 2; h2++)
        qf[h2] = *(const v8bf*)(&Qs[(wave * 16 + rr) * 64 + (((quad + 4 * h2) ^ (rr & 7)) * 8)]);

    v4f Oa[4];
#pragma unroll
    for (int t = 0; t < 4; t++) Oa[t] = (v4f){0.f, 0.f, 0.f, 0.f};
    float m = -3e38f, l = 0.f;

    for (int s0 = 0; s0 < S; s0 += 64) {
        __syncthreads();  // all waves done reading Ks/Vs of previous chunk
        // stage K (DMA, swizzled)
#pragma unroll
        for (int i = 0; i < 2; i++) {
            int r = wave * 16 + i * 8 + drow;
            __builtin_amdgcn_global_load_lds(
                (__attribute__((address_space(1))) void*)(Kp + (size_t)(b * S + s0 + r) * ldkv + h * 64 + dchunk * 8),
                (__attribute__((address_space(3))) void*)(&Ks[(wave * 16 + i * 8) * 64]), 16, 0, 0);
        }
        // stage V (plain rows, pad 66)
        {
            int vr = tid >> 2, c0 = (tid & 3) * 16;
            const u16* src = Vp + (size_t)(b * S + s0 + vr) * ldkv + h * 64 + c0;
            uint4 u0 = *(const uint4*)(src);
            uint4 u1 = *(const uint4*)(src + 8);
            unsigned* dst = (unsigned*)(&Vs[vr * 66 + c0]);
            dst[0] = u0.x; dst[1] = u0.y; dst[2] = u0.z; dst[3] = u0.w;
            dst[4] = u1.x; dst[5] = u1.y; dst[6] = u1.z; dst[7] = u1.w;
        }
        __syncthreads();  // K DMA + V writes visible

        // ---- S^T = K · Q^T ----
        v4f Sf[4];
#pragma unroll
        for (int t = 0; t < 4; t++) Sf[t] = (v4f){0.f, 0.f, 0.f, 0.f};
#pragma unroll
        for (int t = 0; t < 4; t++)
#pragma unroll
            for (int h2 = 0; h2 < 2; h2++) {
                v8bf kf = *(const v8bf*)(&Ks[(16 * t + rr) * 64 + (((quad + 4 * h2) ^ (rr & 7)) * 8)]);
                Sf[t] = __builtin_amdgcn_mfma_f32_16x16x32_bf16(kf, qf[h2], Sf[t], 0, 0, 0);
            }
        // ---- online softmax over kv (rows) for fixed q (=lane&15) ----
        float mx = -3e38f;
#pragma unroll
        for (int t = 0; t < 4; t++)
#pragma unroll
            for (int r = 0; r < 4; r++) {
                float v = Sf[t][r] * ATTN_SCL;
                Sf[t][r] = v;
                mx = fmaxf(mx, v);
            }
        mx = fmaxf(mx, __shfl_xor(mx, 16, 64));
        mx = fmaxf(mx, __shfl_xor(mx, 32, 64));
        float mn = fmaxf(m, mx);
        float alpha = __expf(m - mn);
        float su = 0.f;
#pragma unroll
        for (int t = 0; t < 4; t++)
#pragma unroll
            for (int r = 0; r < 4; r++) {
                float p = __expf(Sf[t][r] - mn);
                Sf[t][r] = p;
                su += p;
            }
        su += __shfl_xor(su, 16, 64);
        su += __shfl_xor(su, 32, 64);
        l = l * alpha + su;
        m = mn;
#pragma unroll
        for (int t = 0; t < 4; t++)
#pragma unroll
            for (int r = 0; r < 4; r++) Oa[t][r] *= alpha;
        // ---- write P^T frag rows to per-wave LDS as P[q][kv] (bf16) ----
#pragma unroll
        for (int t = 0; t < 4; t++) {
            ushort4 pw = make_ushort4(f2b(Sf[t][0]), f2b(Sf[t][1]), f2b(Sf[t][2]), f2b(Sf[t][3]));
            *(ushort4*)(&Ps[wave][rr * 72 + 16 * t + 4 * quad]) = pw;
        }
        // ---- O^T += V^T · P^T ----
        v8bf pf[2];
#pragma unroll
        for (int h2 = 0; h2 < 2; h2++)
            pf[h2] = *(const v8bf*)(&Ps[wave][rr * 72 + quad * 8 + 32 * h2]);
#pragma unroll
        for (int t = 0; t < 4; t++)
#pragma unroll
            for (int h2 = 0; h2 < 2; h2++) {
                union { v8bf v; u16 e[8]; } vf;
#pragma unroll
                for (int j = 0; j < 8; j++)
                    vf.e[j] = Vs[(quad * 8 + j + 32 * h2) * 66 + 16 * t + rr];
                Oa[t] = __builtin_amdgcn_mfma_f32_16x16x32_bf16(vf.v, pf[h2], Oa[t], 0, 0, 0);
            }
    }
    // ---- epilogue: O^T/l -> staging [q][d] -> coalesced global ----
    float inv = 1.f / l;
#pragma unroll
    for (int t = 0; t < 4; t++) {
        ushort4 ow = make_ushort4(f2b(Oa[t][0] * inv), f2b(Oa[t][1] * inv),
                                  f2b(Oa[t][2] * inv), f2b(Oa[t][3] * inv));
        *(ushort4*)(&Ps[wave][rr * 72 + 16 * t + 4 * quad]) = ow;
    }
#pragma unroll
    for (int j = 0; j < 2; j++) {
        int idx = j * 64 + lane;
        int ql = idx >> 3, c = (idx & 7) * 8;
        uint4 u = *(const uint4*)(&Ps[wave][ql * 72 + c]);
        *(uint4*)(Out + (size_t)(b * Nq + q0 + wave * 16 + ql) * 1024 + h * 64 + c) = u;
    }
}

// ---------------------------------------------------------------------------
extern "C" void kernel_launch(void* const* d_in, const int* in_sizes, int n_in,
                              void* d_out, int out_size, void* d_ws, size_t ws_size,
                              hipStream_t stream) {
    (void)in_sizes; (void)n_in; (void)out_size;
    const float* x    = (const float*)d_in[0];
    const float* ctx  = (const float*)d_in[1];
    const float* cond = (const float*)d_in[2];
    const float* n1w = (const float*)d_in[3];  const float* n1mw = (const float*)d_in[4];  const float* n1mb = (const float*)d_in[5];
    const float* n2w = (const float*)d_in[6];  const float* n2mw = (const float*)d_in[7];  const float* n2mb = (const float*)d_in[8];
    const float* n3w = (const float*)d_in[9];  const float* n3mw = (const float*)d_in[10]; const float* n3mb = (const float*)d_in[11];
    const float* saq = (const float*)d_in[12]; const float* sak = (const float*)d_in[13];
    const float* sav = (const float*)d_in[14]; const float* sao = (const float*)d_in[15];
    const float* caq = (const float*)d_in[16]; const float* cak = (const float*)d_in[17];
    const float* cav = (const float*)d_in[18]; const float* cao = (const float*)d_in[19];
    const float* ffg = (const float*)d_in[20]; const float* ffu = (const float*)d_in[21];
    const float* ffd = (const float*)d_in[22];
    float* out = (float*)d_out;  // reference output dtype is float32

    char* ws = (char*)d_ws;
    size_t off = 0;
    auto alloc = [&](size_t bytes) { void* p = ws + off; off += (bytes + 255) & ~(size_t)255; return p; };
    float* xf   = (float*)alloc((size_t)4194304 * 4);   // running x, fp32      16 MB
    u16* normed = (u16*)alloc((size_t)4194304 * 2);     //                       8 MB
    u16* qkv    = (u16*)alloc((size_t)12582912 * 2);    // SA qkv / CA q        24 MB
    u16* kvb    = (u16*)alloc((size_t)33554432 * 2);    // CA kv / FFN hidden   64 MB
    u16* obuf   = (u16*)alloc((size_t)4194304 * 2);     //                       8 MB
    float* mod3 = (float*)alloc((size_t)73728 * 4);     //                      0.3 MB
    // bf16 pre-converted operands (new path; only used if workspace fits)
    const size_t MEG = 1048576;
    u16* ctxb = (u16*)alloc((size_t)33554432 * 2);      // ctx as bf16          64 MB
    u16* wb   = (u16*)alloc((size_t)22 * MEG * 2);      // all weights, bf16    44 MB
    u16* saq_b = wb;            u16* sak_b = wb + 1 * MEG;  u16* sav_b = wb + 2 * MEG;
    u16* sao_b = wb + 3 * MEG;  u16* caq_b = wb + 4 * MEG;
    u16* cakv_b = wb + 5 * MEG;                              // cak(2M) + cav(2M) contiguous
    u16* cak_b = wb + 5 * MEG;  u16* cav_b = wb + 7 * MEG;
    u16* cao_b = wb + 9 * MEG;
    u16* ffg_b = wb + 10 * MEG; u16* ffu_b = wb + 14 * MEG; u16* ffd_b = wb + 18 * MEG;
    const bool CVT = (ws_size >= off);  // ~229 MiB needed for the bf16 path

    hipMemcpyAsync(xf, x, (size_t)4194304 * 4, hipMemcpyDeviceToDevice, stream);
    mod_kernel<<<18432, 256, 0, stream>>>(cond, n1mw, n1mb, n2mw, n2mb, n3mw, n3mb, mod3);

    if (CVT) {
        // ---- one-time fp32->bf16 conversion of ctx + all GEMM weights ----
        cvt4_kernel<<<dim3(512, 4), 256, 0, stream>>>(
            saq, saq_b, (int)MEG, sak, sak_b, (int)MEG,
            sav, sav_b, (int)MEG, sao, sao_b, (int)MEG);
        cvt4_kernel<<<dim3(1024, 4), 256, 0, stream>>>(
            cak, cak_b, (int)(2 * MEG), cav, cav_b, (int)(2 * MEG),
            caq, caq_b, (int)MEG, cao, cao_b, (int)MEG);
        cvt4_kernel<<<dim3(2048, 3), 256, 0, stream>>>(
            ffg, ffg_b, (int)(4 * MEG), ffu, ffu_b, (int)(4 * MEG),
            ffd, ffd_b, (int)(4 * MEG), nullptr, nullptr, 0);
        cvt4_kernel<<<dim3(16384, 1), 256, 0, stream>>>(
            ctx, ctxb, 33554432, nullptr, nullptr, 0,
            nullptr, nullptr, 0, nullptr, nullptr, 0);

        // ---- self-attention (QKV fused: saq/sak/sav contiguous -> N=3072) ----
        adarms_kernel<<<4096, 256, 0, stream>>>(xf, n1w, mod3, normed);
        gemm_bt<u16, u16, 0><<<dim3(24, 32), 256, 0, stream>>>(normed, saq_b, qkv, nullptr, nullptr, nullptr, 4096, 3072, 1024, 3072, 0);
        attn_kernel<<<dim3(8, 16, 8), 256, 0, stream>>>(qkv, 3072, qkv + 1024, qkv + 2048, 3072, obuf, 512);
        gemm_bt<u16, u16, 1><<<dim3(8, 32), 256, 0, stream>>>(obuf, sao_b, nullptr, nullptr, xf, mod3, 4096, 1024, 1024, 1024, 0);

        // ---- cross-attention (KV fused: cak/cav contiguous -> N=2048) ----
        adarms_kernel<<<4096, 256, 0, stream>>>(xf, n2w, mod3 + 24576, normed);
        gemm_bt<u16, u16, 0><<<dim3(8, 32), 256, 0, stream>>>(normed, caq_b, qkv, nullptr, nullptr, nullptr, 4096, 1024, 1024, 1024, 0);
        gemm_bt<u16, u16, 0><<<dim3(16, 128), 256, 0, stream>>>(ctxb, cakv_b, kvb, nullptr, nullptr, nullptr, 16384, 2048, 2048, 2048, 0);
        attn_kernel<<<dim3(8, 16, 8), 256, 0, stream>>>(qkv, 1024, kvb, kvb + 1024, 2048, obuf, 2048);
        gemm_bt<u16, u16, 1><<<dim3(8, 32), 256, 0, stream>>>(obuf, cao_b, nullptr, nullptr, xf, mod3 + 24576, 4096, 1024, 1024, 1024, 0);

        // ---- SwiGLU MLP ----
        adarms_kernel<<<4096, 256, 0, stream>>>(xf, n3w, mod3 + 49152, normed);
        gemm_bt<u16, u16, 0><<<dim3(32, 32), 256, 0, stream>>>(normed, ffg_b, kvb, nullptr, nullptr, nullptr, 4096, 4096, 1024, 4096, 0);
        gemm_bt<u16, u16, 2><<<dim3(32, 32), 256, 0, stream>>>(normed, ffu_b, kvb, nullptr, nullptr, nullptr, 4096, 4096, 1024, 4096, 0);
        gemm_bt<u16, u16, 3><<<dim3(8, 32), 256, 0, stream>>>(kvb, ffd_b, nullptr, out, xf, mod3 + 49152, 4096, 1024, 4096, 1024, 0);
    } else {
        // ---- fallback: previously-verified fp32-staging path ----
        adarms_kernel<<<4096, 256, 0, stream>>>(xf, n1w, mod3, normed);
        gemm_bt<u16, float, 0><<<dim3(8, 32), 256, 0, stream>>>(normed, saq, qkv, nullptr, nullptr, nullptr, 4096, 1024, 1024, 3072, 0);
        gemm_bt<u16, float, 0><<<dim3(8, 32), 256, 0, stream>>>(normed, sak, qkv, nullptr, nullptr, nullptr, 4096, 1024, 1024, 3072, 1024);
        gemm_bt<u16, float, 0><<<dim3(8, 32), 256, 0, stream>>>(normed, sav, qkv, nullptr, nullptr, nullptr, 4096, 1024, 1024, 3072, 2048);
        attn_kernel<<<dim3(8, 16, 8), 256, 0, stream>>>(qkv, 3072, qkv + 1024, qkv + 2048, 3072, obuf, 512);
        gemm_bt<u16, float, 1><<<dim3(8, 32), 256, 0, stream>>>(obuf, sao, nullptr, nullptr, xf, mod3, 4096, 1024, 1024, 1024, 0);

        adarms_kernel<<<4096, 256, 0, stream>>>(xf, n2w, mod3 + 24576, normed);
        gemm_bt<u16, float, 0><<<dim3(8, 32), 256, 0, stream>>>(normed, caq, qkv, nullptr, nullptr, nullptr, 4096, 1024, 1024, 1024, 0);
        gemm_bt<float, float, 0><<<dim3(8, 128), 256, 0, stream>>>(ctx, cak, kvb, nullptr, nullptr, nullptr, 16384, 1024, 2048, 2048, 0);
        gemm_bt<float, float, 0><<<dim3(8, 128), 256, 0, stream>>>(ctx, cav, kvb, nullptr, nullptr, nullptr, 16384, 1024, 2048, 2048, 1024);
        attn_kernel<<<dim3(8, 16, 8), 256, 0, stream>>>(qkv, 1024, kvb, kvb + 1024, 2048, obuf, 2048);
        gemm_bt<u16, float, 1><<<dim3(8, 32), 256, 0, stream>>>(obuf, cao, nullptr, nullptr, xf, mod3 + 24576, 4096, 1024, 1024, 1024, 0);

        adarms_kernel<<<4096, 256, 0, stream>>>(xf, n3w, mod3 + 49152, normed);
        gemm_bt<u16, float, 0><<<dim3(32, 32), 256, 0, stream>>>(normed, ffg, kvb, nullptr, nullptr, nullptr, 4096, 4096, 1024, 4096, 0);
        gemm_bt<u16, float, 2><<<dim3(32, 32), 256, 0, stream>>>(normed, ffu, kvb, nullptr, nullptr, nullptr, 4096, 4096, 1024, 4096, 0);
        gemm_bt<u16, float, 3><<<dim3(8, 32), 256, 0, stream>>>(kvb, ffd, nullptr, out, xf, mod3 + 49152, 4096, 1024, 4096, 1024, 0);
    }
}

// Round 2
// 975.338 us; speedup vs baseline: 1.5248x; 1.0960x over previous
//
#include <hip/hip_runtime.h>

typedef unsigned short u16;
typedef __bf16 v8bf __attribute__((ext_vector_type(8)));
typedef float  v4f  __attribute__((ext_vector_type(4)));

__device__ __forceinline__ float b2f(u16 h) { return __uint_as_float(((unsigned)h) << 16); }
__device__ __forceinline__ u16 f2b(float f) {
    unsigned u = __float_as_uint(f);
    unsigned r = (u + 0x7FFFu + ((u >> 16) & 1u)) >> 16;  // RNE
    return (u16)r;
}

// ---------------------------------------------------------------------------
// fp32 -> bf16 bulk conversion; 4 independent tensors per launch.
__global__ __launch_bounds__(256) void cvt4_kernel(
    const float* __restrict__ s0, u16* __restrict__ d0, int n0,
    const float* __restrict__ s1, u16* __restrict__ d1, int n1,
    const float* __restrict__ s2, u16* __restrict__ d2, int n2,
    const float* __restrict__ s3, u16* __restrict__ d3, int n3) {
    const float* s; u16* d; int n;
    switch (blockIdx.y) {
        case 0:  s = s0; d = d0; n = n0; break;
        case 1:  s = s1; d = d1; n = n1; break;
        case 2:  s = s2; d = d2; n = n2; break;
        default: s = s3; d = d3; n = n3; break;
    }
    int i = blockIdx.x * 256 + threadIdx.x;   // handles elements [8i, 8i+8)
    if (i * 8 < n) {
        float4 a = ((const float4*)s)[i * 2];
        float4 b = ((const float4*)s)[i * 2 + 1];
        ((ushort4*)d)[i * 2]     = make_ushort4(f2b(a.x), f2b(a.y), f2b(a.z), f2b(a.w));
        ((ushort4*)d)[i * 2 + 1] = make_ushort4(f2b(b.x), f2b(b.y), f2b(b.z), f2b(b.w));
    }
}

// ---------------------------------------------------------------------------
// mod3[p][b][j] = sum_k cond[b][k]*mw_p[j][k] + mb_p[j]
__global__ __launch_bounds__(256) void mod_kernel(
    const float* __restrict__ cond,
    const float* __restrict__ mw0, const float* __restrict__ mb0,
    const float* __restrict__ mw1, const float* __restrict__ mb1,
    const float* __restrict__ mw2, const float* __restrict__ mb2,
    float* __restrict__ mod3) {
    const int tid = threadIdx.x, wave = tid >> 6, lane = tid & 63;
    int job = blockIdx.x * 4 + wave;  // 73728 jobs
    int p = job / 24576, r = job % 24576;
    int b = r / 3072, j = r % 3072;
    const float* mw = p == 0 ? mw0 : (p == 1 ? mw1 : mw2);
    const float* mb = p == 0 ? mb0 : (p == 1 ? mb1 : mb2);
    const float4* c = (const float4*)(cond + b * 1024);
    const float4* wr = (const float4*)(mw + (size_t)j * 1024);
    float s = 0.f;
#pragma unroll
    for (int t = 0; t < 4; t++) {
        float4 cv = c[lane + t * 64], wv = wr[lane + t * 64];
        s += cv.x * wv.x + cv.y * wv.y + cv.z * wv.z + cv.w * wv.w;
    }
#pragma unroll
    for (int o = 32; o > 0; o >>= 1) s += __shfl_xor(s, o, 64);
    if (lane == 0) mod3[(size_t)p * 24576 + b * 3072 + j] = s + mb[j];
}

// ---------------------------------------------------------------------------
// AdaRMS: bf16 out = x*rsqrt(mean(x^2)+eps)*w*(1+scale)+shift
__global__ __launch_bounds__(256) void adarms_kernel(
    const float* __restrict__ Xf, const float* __restrict__ w,
    const float* __restrict__ mod, u16* __restrict__ Out) {
    __shared__ float red[4];
    const int row = blockIdx.x, tid = threadIdx.x;
    const int bidx = row >> 9;
    const float* x = Xf + (size_t)row * 1024;
    float4 v = *(const float4*)(x + tid * 4);
    float s = v.x * v.x + v.y * v.y + v.z * v.z + v.w * v.w;
#pragma unroll
    for (int o = 32; o > 0; o >>= 1) s += __shfl_xor(s, o, 64);
    if ((tid & 63) == 0) red[tid >> 6] = s;
    __syncthreads();
    float tot = red[0] + red[1] + red[2] + red[3];
    float norm = 1.0f / sqrtf(tot * (1.f / 1024.f) + 1e-6f);
    const float* mo = mod + (size_t)bidx * 3072;
    int d = tid * 4;
    float4 wv = *(const float4*)(w + d);
    const float xv[4] = {v.x, v.y, v.z, v.w};
    const float wa[4] = {wv.x, wv.y, wv.z, wv.w};
    u16 o4[4];
#pragma unroll
    for (int t = 0; t < 4; t++) {
        float sc = mo[d + t], sh = mo[1024 + d + t];
        o4[t] = f2b(xv[t] * norm * wa[t] * (1.f + sc) + sh);
    }
    *(ushort4*)(Out + (size_t)row * 1024 + d) = make_ushort4(o4[0], o4[1], o4[2], o4[3]);
}

// ---------------------------------------------------------------------------
// Staging 128 rows x 32 k into LDS as bf16 (128^2 GEMM).
template <typename T>
__device__ __forceinline__ void stage_tile(const T* __restrict__ G, int ldg, int row0,
                                           int k0, u16* lds, int tid) {
    if constexpr (sizeof(T) == 2) {
        const int wave = tid >> 6, lane = tid & 63;
        const int r4 = lane >> 2, c8 = (lane & 3) * 8;
#pragma unroll
        for (int i = 0; i < 2; i++) {
            int row = wave * 32 + i * 16;
            __builtin_amdgcn_global_load_lds(
                (__attribute__((address_space(1))) void*)((const u16*)G + (size_t)(row0 + row + r4) * ldg + k0 + c8),
                (__attribute__((address_space(3))) void*)(&lds[row * 32]), 16, 0, 0);
        }
    } else {
        const int row = tid >> 1, col = (tid & 1) * 16;
        const float* src = (const float*)G + (size_t)(row0 + row) * ldg + k0 + col;
        float4 f0 = *(const float4*)(src);
        float4 f1 = *(const float4*)(src + 4);
        float4 f2 = *(const float4*)(src + 8);
        float4 f3 = *(const float4*)(src + 12);
        ushort4* dst = (ushort4*)(&lds[row * 32 + col]);
        dst[0] = make_ushort4(f2b(f0.x), f2b(f0.y), f2b(f0.z), f2b(f0.w));
        dst[1] = make_ushort4(f2b(f1.x), f2b(f1.y), f2b(f1.z), f2b(f1.w));
        dst[2] = make_ushort4(f2b(f2.x), f2b(f2.y), f2b(f2.z), f2b(f2.w));
        dst[3] = make_ushort4(f2b(f3.x), f2b(f3.y), f2b(f3.z), f2b(f3.w));
    }
}

// ---------------------------------------------------------------------------
// 128x128 GEMM (kept for N=1024 shapes + fp32 fallback). C = A @ Bw^T.
// MODE 0: Cb = bf16(acc)   MODE 1: Xf += gate*acc
// MODE 2: Cb = bf16(silu(Cb)*acc)   MODE 3: Cf = Xf + gate*acc
template <typename TA, typename TB, int MODE>
__global__ __launch_bounds__(256) void gemm_bt(
    const TA* __restrict__ A, const TB* __restrict__ Bw,
    u16* __restrict__ Cb, float* __restrict__ Cf,
    float* __restrict__ Xf, const float* __restrict__ mod,
    int M, int N, int K, int ldc, int coff) {
    __shared__ u16 As[128 * 32];
    __shared__ u16 Bs[128 * 32];
    const int tid = threadIdx.x;
    const int wave = tid >> 6, lane = tid & 63;
    // T1 XCD-aware swizzle (all grids have nwg % 8 == 0)
    const int gx = gridDim.x, nwg = gx * gridDim.y;
    int bid = blockIdx.y * gx + blockIdx.x;
    bid = (bid & 7) * (nwg >> 3) + (bid >> 3);
    const int m0 = (bid / gx) * 128, n0 = (bid % gx) * 128;
    const int wm = (wave >> 1) * 64, wn = (wave & 1) * 64;
    const int kq = lane >> 4, rr = lane & 15;

    v4f acc[4][4];
#pragma unroll
    for (int i = 0; i < 4; i++)
#pragma unroll
        for (int j = 0; j < 4; j++) acc[i][j] = (v4f){0.f, 0.f, 0.f, 0.f};

    for (int k0 = 0; k0 < K; k0 += 32) {
        __syncthreads();
        stage_tile<TA>(A, K, m0, k0, As, tid);
        stage_tile<TB>(Bw, K, n0, k0, Bs, tid);
        __syncthreads();
        v8bf a[4], b[4];
#pragma unroll
        for (int i = 0; i < 4; i++) a[i] = *(const v8bf*)(&As[(wm + i * 16 + rr) * 32 + kq * 8]);
#pragma unroll
        for (int j = 0; j < 4; j++) b[j] = *(const v8bf*)(&Bs[(wn + j * 16 + rr) * 32 + kq * 8]);
#pragma unroll
        for (int i = 0; i < 4; i++)
#pragma unroll
            for (int j = 0; j < 4; j++)
                acc[i][j] = __builtin_amdgcn_mfma_f32_16x16x32_bf16(a[i], b[j], acc[i][j], 0, 0, 0);
    }

    const int quad = lane >> 4, cl = lane & 15;
#pragma unroll
    for (int i = 0; i < 4; i++)
#pragma unroll
        for (int j = 0; j < 4; j++)
#pragma unroll
            for (int r = 0; r < 4; r++) {
                int row = m0 + wm + i * 16 + quad * 4 + r;
                int col = n0 + wn + j * 16 + cl;
                size_t idx = (size_t)row * ldc + coff + col;
                float v = acc[i][j][r];
                if constexpr (MODE == 0) {
                    Cb[idx] = f2b(v);
                } else if constexpr (MODE == 1) {
                    float g = mod[(row >> 9) * 3072 + 2048 + col];
                    Xf[(size_t)row * 1024 + col] += g * v;
                } else if constexpr (MODE == 2) {
                    float gv = b2f(Cb[idx]);
                    float s = gv / (1.f + __expf(-gv));
                    Cb[idx] = f2b(s * v);
                } else {
                    float g = mod[(row >> 9) * 3072 + 2048 + col];
                    Cf[idx] = Xf[(size_t)row * 1024 + col] + g * v;
                }
            }
}

// ---------------------------------------------------------------------------
// 256x256 / BK=64 8-wave GEMM, 4-phase K-tile schedule with counted vmcnt
// (T3+T4), XOR-swizzled LDS (T2, both-sides via pre-swizzled global source),
// setprio around MFMA clusters (T5), XCD bid swizzle (T1).
//
// LDS layout per (buf, khalf): 128 superrows x 128B; superrow sr = row/2 of
// a [256 rows x 32 k] half; chunk c (16B) holds logical chunk c ^ (sr&7).
// Logical chunk c = (row&1)*4 + k/8. Staged by global_load_lds with the
// inverse permutation applied to the per-lane GLOBAL source address
// (linear LDS dest, rule #21).
__device__ __forceinline__ void stage256(const u16* __restrict__ G, int ldg,
                                         int rowbase, int kcol, u16* lds,
                                         int w, int lane) {
    const int csrc = (lane & 7) ^ (lane >> 3);
    const int rof = csrc >> 2, kof = (csrc & 3) * 8;
#pragma unroll
    for (int q = 0; q < 2; q++) {
        int s = q * 8 + w;                 // 1KB slot: superrows 8s..8s+7
        int sr = s * 8 + (lane >> 3);
        __builtin_amdgcn_global_load_lds(
            (__attribute__((address_space(1))) void*)(G + (size_t)(rowbase + sr * 2 + rof) * ldg + kcol + kof),
            (__attribute__((address_space(3))) void*)(lds + s * 512), 16, 0, 0);
    }
}

__device__ __forceinline__ v8bf frag256(const u16* lds, int r, int kq) {
    int sr = r >> 1;
    int cp = (((r & 1) << 2) | kq) ^ (sr & 7);
    return *(const v8bf*)(lds + sr * 64 + cp * 8);
}

template <int MODE>  // 0: Cb=bf16(acc); 2: Cb=bf16(silu(Cb)*acc)
__global__ __launch_bounds__(512, 2) void gemm256(
    const u16* __restrict__ A, const u16* __restrict__ Bw,
    u16* __restrict__ Cb, int K, int ldc, int coff) {
    __shared__ u16 As[2][2][8192];   // [buf][khalf][128 superrows * 64]
    __shared__ u16 Bs[2][2][8192];
    const int tid = threadIdx.x, w = tid >> 6, lane = tid & 63;
    const int gx = gridDim.x, nwg = gx * gridDim.y;
    int bid = blockIdx.y * gx + blockIdx.x;
    bid = (bid & 7) * (nwg >> 3) + (bid >> 3);      // T1 (nwg % 8 == 0)
    const int n0 = (bid % gx) * 256, m0 = (bid / gx) * 256;
    const int wm = w >> 2, wn = w & 3;              // 2 x 4 wave grid
    const int rr = lane & 15, kq = lane >> 4;

    v4f acc[8][4];
#pragma unroll
    for (int i = 0; i < 8; i++)
#pragma unroll
        for (int j = 0; j < 4; j++) acc[i][j] = (v4f){0.f, 0.f, 0.f, 0.f};

    const int nt = K >> 6;
    // prologue: stage tile 0 (units: A-k0, B-k0, A-k1, B-k1)
    stage256(A, K, m0, 0, &As[0][0][0], w, lane);
    stage256(Bw, K, n0, 0, &Bs[0][0][0], w, lane);
    stage256(A, K, m0, 32, &As[0][1][0], w, lane);
    stage256(Bw, K, n0, 32, &Bs[0][1][0], w, lane);
    asm volatile("s_waitcnt vmcnt(4)" ::: "memory");  // k-half 0 resident
    __builtin_amdgcn_s_barrier();

    for (int t = 0; t < nt; ++t) {
        const int buf = t & 1;
        const bool st = (t + 1 < nt);
        const int k1 = (t + 1) << 6;
        const u16* A0 = &As[buf][0][0];
        const u16* B0 = &Bs[buf][0][0];
        const u16* A1 = &As[buf][1][0];
        const u16* B1 = &Bs[buf][1][0];
        u16* nA0 = &As[buf ^ 1][0][0];
        u16* nB0 = &Bs[buf ^ 1][0][0];
        u16* nA1 = &As[buf ^ 1][1][0];
        u16* nB1 = &Bs[buf ^ 1][1][0];
        v8bf af[4], bf[4];

        // ---- phase 0: khalf 0, mi 0..3 (loads B-frags for khalf 0) ----
#pragma unroll
        for (int j = 0; j < 4; j++) bf[j] = frag256(B0, wn * 64 + j * 16 + rr, kq);
#pragma unroll
        for (int i = 0; i < 4; i++) af[i] = frag256(A0, wm * 128 + i * 16 + rr, kq);
        if (st) stage256(A, K, m0, k1, nA0, w, lane);
        __builtin_amdgcn_s_barrier();
        asm volatile("s_waitcnt lgkmcnt(0)" ::: "memory");
        __builtin_amdgcn_sched_barrier(0);
        __builtin_amdgcn_s_setprio(1);
#pragma unroll
        for (int i = 0; i < 4; i++)
#pragma unroll
            for (int j = 0; j < 4; j++)
                acc[i][j] = __builtin_amdgcn_mfma_f32_16x16x32_bf16(af[i], bf[j], acc[i][j], 0, 0, 0);
        __builtin_amdgcn_s_setprio(0);
        __builtin_amdgcn_s_barrier();

        // ---- phase 1: khalf 0, mi 4..7 (reuses bf) ----
#pragma unroll
        for (int i = 0; i < 4; i++) af[i] = frag256(A0, wm * 128 + (4 + i) * 16 + rr, kq);
        if (st) {
            stage256(Bw, K, n0, k1, nB0, w, lane);
            asm volatile("s_waitcnt vmcnt(4)" ::: "memory");  // this tile's khalf 1 resident
        } else {
            asm volatile("s_waitcnt vmcnt(0)" ::: "memory");
        }
        __builtin_amdgcn_s_barrier();
        asm volatile("s_waitcnt lgkmcnt(0)" ::: "memory");
        __builtin_amdgcn_sched_barrier(0);
        __builtin_amdgcn_s_setprio(1);
#pragma unroll
        for (int i = 0; i < 4; i++)
#pragma unroll
            for (int j = 0; j < 4; j++)
                acc[4 + i][j] = __builtin_amdgcn_mfma_f32_16x16x32_bf16(af[i], bf[j], acc[4 + i][j], 0, 0, 0);
        __builtin_amdgcn_s_setprio(0);
        __builtin_amdgcn_s_barrier();

        // ---- phase 2: khalf 1, mi 0..3 (loads B-frags for khalf 1) ----
#pragma unroll
        for (int j = 0; j < 4; j++) bf[j] = frag256(B1, wn * 64 + j * 16 + rr, kq);
#pragma unroll
        for (int i = 0; i < 4; i++) af[i] = frag256(A1, wm * 128 + i * 16 + rr, kq);
        if (st) stage256(A, K, m0, k1 + 32, nA1, w, lane);
        __builtin_amdgcn_s_barrier();
        asm volatile("s_waitcnt lgkmcnt(0)" ::: "memory");
        __builtin_amdgcn_sched_barrier(0);
        __builtin_amdgcn_s_setprio(1);
#pragma unroll
        for (int i = 0; i < 4; i++)
#pragma unroll
            for (int j = 0; j < 4; j++)
                acc[i][j] = __builtin_amdgcn_mfma_f32_16x16x32_bf16(af[i], bf[j], acc[i][j], 0, 0, 0);
        __builtin_amdgcn_s_setprio(0);
        __builtin_amdgcn_s_barrier();

        // ---- phase 3: khalf 1, mi 4..7 ----
#pragma unroll
        for (int i = 0; i < 4; i++) af[i] = frag256(A1, wm * 128 + (4 + i) * 16 + rr, kq);
        if (st) {
            stage256(Bw, K, n0, k1 + 32, nB1, w, lane);
            asm volatile("s_waitcnt vmcnt(4)" ::: "memory");  // next tile's khalf 0 resident
        }
        __builtin_amdgcn_s_barrier();
        asm volatile("s_waitcnt lgkmcnt(0)" ::: "memory");
        __builtin_amdgcn_sched_barrier(0);
        __builtin_amdgcn_s_setprio(1);
#pragma unroll
        for (int i = 0; i < 4; i++)
#pragma unroll
            for (int j = 0; j < 4; j++)
                acc[4 + i][j] = __builtin_amdgcn_mfma_f32_16x16x32_bf16(af[i], bf[j], acc[4 + i][j], 0, 0, 0);
        __builtin_amdgcn_s_setprio(0);
        __builtin_amdgcn_s_barrier();
    }

    // ---- epilogue ----
    const int quad = lane >> 4, cl = lane & 15;
#pragma unroll
    for (int i = 0; i < 8; i++)
#pragma unroll
        for (int j = 0; j < 4; j++)
#pragma unroll
            for (int r = 0; r < 4; r++) {
                int row = m0 + wm * 128 + i * 16 + quad * 4 + r;
                int col = n0 + wn * 64 + j * 16 + cl;
                size_t idx = (size_t)row * ldc + coff + col;
                float v = acc[i][j][r];
                if constexpr (MODE == 0) {
                    Cb[idx] = f2b(v);
                } else {
                    float gv = b2f(Cb[idx]);
                    float s = gv / (1.f + __expf(-gv));
                    Cb[idx] = f2b(s * v);
                }
            }
}

// ---------------------------------------------------------------------------
// MFMA flash attention (unchanged).
#define ATTN_SCL 0.125f
__global__ __launch_bounds__(256) void attn_kernel(
    const u16* __restrict__ Q, int ldq,
    const u16* __restrict__ Kp, const u16* __restrict__ Vp, int ldkv,
    u16* __restrict__ Out, int S) {
    __shared__ u16 Ks[64 * 64];
    __shared__ u16 Qs[64 * 64];
    __shared__ u16 Vs[64 * 66];
    __shared__ u16 Ps[4][16 * 72];
    const int tid = threadIdx.x, wave = tid >> 6, lane = tid & 63;
    const int b = blockIdx.z, h = blockIdx.y, q0 = blockIdx.x * 64;
    const int Nq = 512;
    const int rr = lane & 15, quad = lane >> 4;
    const int drow = lane >> 3;
    const int dchunk = (lane & 7) ^ drow;

#pragma unroll
    for (int i = 0; i < 2; i++) {
        int r = wave * 16 + i * 8 + drow;
        __builtin_amdgcn_global_load_lds(
            (__attribute__((address_space(1))) void*)(Q + (size_t)(b * Nq + q0 + r) * ldq + h * 64 + dchunk * 8),
            (__attribute__((address_space(3))) void*)(&Qs[(wave * 16 + i * 8) * 64]), 16, 0, 0);
    }
    __syncthreads();

    v8bf qf[2];
#pragma unroll
    for (int h2 = 0; h2 < 2; h2++)
        qf[h2] = *(const v8bf*)(&Qs[(wave * 16 + rr) * 64 + (((quad + 4 * h2) ^ (rr & 7)) * 8)]);

    v4f Oa[4];
#pragma unroll
    for (int t = 0; t < 4; t++) Oa[t] = (v4f){0.f, 0.f, 0.f, 0.f};
    float m = -3e38f, l = 0.f;

    for (int s0 = 0; s0 < S; s0 += 64) {
        __syncthreads();
#pragma unroll
        for (int i = 0; i < 2; i++) {
            int r = wave * 16 + i * 8 + drow;
            __builtin_amdgcn_global_load_lds(
                (__attribute__((address_space(1))) void*)(Kp + (size_t)(b * S + s0 + r) * ldkv + h * 64 + dchunk * 8),
                (__attribute__((address_space(3))) void*)(&Ks[(wave * 16 + i * 8) * 64]), 16, 0, 0);
        }
        {
            int vr = tid >> 2, c0 = (tid & 3) * 16;
            const u16* src = Vp + (size_t)(b * S + s0 + vr) * ldkv + h * 64 + c0;
            uint4 u0 = *(const uint4*)(src);
            uint4 u1 = *(const uint4*)(src + 8);
            unsigned* dst = (unsigned*)(&Vs[vr * 66 + c0]);
            dst[0] = u0.x; dst[1] = u0.y; dst[2] = u0.z; dst[3] = u0.w;
            dst[4] = u1.x; dst[5] = u1.y; dst[6] = u1.z; dst[7] = u1.w;
        }
        __syncthreads();

        v4f Sf[4];
#pragma unroll
        for (int t = 0; t < 4; t++) Sf[t] = (v4f){0.f, 0.f, 0.f, 0.f};
#pragma unroll
        for (int t = 0; t < 4; t++)
#pragma unroll
            for (int h2 = 0; h2 < 2; h2++) {
                v8bf kf = *(const v8bf*)(&Ks[(16 * t + rr) * 64 + (((quad + 4 * h2) ^ (rr & 7)) * 8)]);
                Sf[t] = __builtin_amdgcn_mfma_f32_16x16x32_bf16(kf, qf[h2], Sf[t], 0, 0, 0);
            }
        float mx = -3e38f;
#pragma unroll
        for (int t = 0; t < 4; t++)
#pragma unroll
            for (int r = 0; r < 4; r++) {
                float v = Sf[t][r] * ATTN_SCL;
                Sf[t][r] = v;
                mx = fmaxf(mx, v);
            }
        mx = fmaxf(mx, __shfl_xor(mx, 16, 64));
        mx = fmaxf(mx, __shfl_xor(mx, 32, 64));
        float mn = fmaxf(m, mx);
        float alpha = __expf(m - mn);
        float su = 0.f;
#pragma unroll
        for (int t = 0; t < 4; t++)
#pragma unroll
            for (int r = 0; r < 4; r++) {
                float p = __expf(Sf[t][r] - mn);
                Sf[t][r] = p;
                su += p;
            }
        su += __shfl_xor(su, 16, 64);
        su += __shfl_xor(su, 32, 64);
        l = l * alpha + su;
        m = mn;
#pragma unroll
        for (int t = 0; t < 4; t++)
#pragma unroll
            for (int r = 0; r < 4; r++) Oa[t][r] *= alpha;
#pragma unroll
        for (int t = 0; t < 4; t++) {
            ushort4 pw = make_ushort4(f2b(Sf[t][0]), f2b(Sf[t][1]), f2b(Sf[t][2]), f2b(Sf[t][3]));
            *(ushort4*)(&Ps[wave][rr * 72 + 16 * t + 4 * quad]) = pw;
        }
        v8bf pf[2];
#pragma unroll
        for (int h2 = 0; h2 < 2; h2++)
            pf[h2] = *(const v8bf*)(&Ps[wave][rr * 72 + quad * 8 + 32 * h2]);
#pragma unroll
        for (int t = 0; t < 4; t++)
#pragma unroll
            for (int h2 = 0; h2 < 2; h2++) {
                union { v8bf v; u16 e[8]; } vf;
#pragma unroll
                for (int j = 0; j < 8; j++)
                    vf.e[j] = Vs[(quad * 8 + j + 32 * h2) * 66 + 16 * t + rr];
                Oa[t] = __builtin_amdgcn_mfma_f32_16x16x32_bf16(vf.v, pf[h2], Oa[t], 0, 0, 0);
            }
    }
    float inv = 1.f / l;
#pragma unroll
    for (int t = 0; t < 4; t++) {
        ushort4 ow = make_ushort4(f2b(Oa[t][0] * inv), f2b(Oa[t][1] * inv),
                                  f2b(Oa[t][2] * inv), f2b(Oa[t][3] * inv));
        *(ushort4*)(&Ps[wave][rr * 72 + 16 * t + 4 * quad]) = ow;
    }
#pragma unroll
    for (int j = 0; j < 2; j++) {
        int idx = j * 64 + lane;
        int ql = idx >> 3, c = (idx & 7) * 8;
        uint4 u = *(const uint4*)(&Ps[wave][ql * 72 + c]);
        *(uint4*)(Out + (size_t)(b * Nq + q0 + wave * 16 + ql) * 1024 + h * 64 + c) = u;
    }
}

// ---------------------------------------------------------------------------
extern "C" void kernel_launch(void* const* d_in, const int* in_sizes, int n_in,
                              void* d_out, int out_size, void* d_ws, size_t ws_size,
                              hipStream_t stream) {
    (void)in_sizes; (void)n_in; (void)out_size;
    const float* x    = (const float*)d_in[0];
    const float* ctx  = (const float*)d_in[1];
    const float* cond = (const float*)d_in[2];
    const float* n1w = (const float*)d_in[3];  const float* n1mw = (const float*)d_in[4];  const float* n1mb = (const float*)d_in[5];
    const float* n2w = (const float*)d_in[6];  const float* n2mw = (const float*)d_in[7];  const float* n2mb = (const float*)d_in[8];
    const float* n3w = (const float*)d_in[9];  const float* n3mw = (const float*)d_in[10]; const float* n3mb = (const float*)d_in[11];
    const float* saq = (const float*)d_in[12]; const float* sak = (const float*)d_in[13];
    const float* sav = (const float*)d_in[14]; const float* sao = (const float*)d_in[15];
    const float* caq = (const float*)d_in[16]; const float* cak = (const float*)d_in[17];
    const float* cav = (const float*)d_in[18]; const float* cao = (const float*)d_in[19];
    const float* ffg = (const float*)d_in[20]; const float* ffu = (const float*)d_in[21];
    const float* ffd = (const float*)d_in[22];
    float* out = (float*)d_out;

    char* ws = (char*)d_ws;
    size_t off = 0;
    auto alloc = [&](size_t bytes) { void* p = ws + off; off += (bytes + 255) & ~(size_t)255; return p; };
    float* xf   = (float*)alloc((size_t)4194304 * 4);
    u16* normed = (u16*)alloc((size_t)4194304 * 2);
    u16* qkv    = (u16*)alloc((size_t)12582912 * 2);
    u16* kvb    = (u16*)alloc((size_t)33554432 * 2);
    u16* obuf   = (u16*)alloc((size_t)4194304 * 2);
    float* mod3 = (float*)alloc((size_t)73728 * 4);
    const size_t MEG = 1048576;
    u16* ctxb = (u16*)alloc((size_t)33554432 * 2);
    u16* wb   = (u16*)alloc((size_t)22 * MEG * 2);
    u16* saq_b = wb;            u16* sak_b = wb + 1 * MEG;  u16* sav_b = wb + 2 * MEG;
    u16* sao_b = wb + 3 * MEG;  u16* caq_b = wb + 4 * MEG;
    u16* cakv_b = wb + 5 * MEG;
    u16* cak_b = wb + 5 * MEG;  u16* cav_b = wb + 7 * MEG;
    u16* cao_b = wb + 9 * MEG;
    u16* ffg_b = wb + 10 * MEG; u16* ffu_b = wb + 14 * MEG; u16* ffd_b = wb + 18 * MEG;
    const bool CVT = (ws_size >= off);

    hipMemcpyAsync(xf, x, (size_t)4194304 * 4, hipMemcpyDeviceToDevice, stream);
    mod_kernel<<<18432, 256, 0, stream>>>(cond, n1mw, n1mb, n2mw, n2mb, n3mw, n3mb, mod3);

    if (CVT) {
        cvt4_kernel<<<dim3(512, 4), 256, 0, stream>>>(
            saq, saq_b, (int)MEG, sak, sak_b, (int)MEG,
            sav, sav_b, (int)MEG, sao, sao_b, (int)MEG);
        cvt4_kernel<<<dim3(1024, 4), 256, 0, stream>>>(
            cak, cak_b, (int)(2 * MEG), cav, cav_b, (int)(2 * MEG),
            caq, caq_b, (int)MEG, cao, cao_b, (int)MEG);
        cvt4_kernel<<<dim3(2048, 3), 256, 0, stream>>>(
            ffg, ffg_b, (int)(4 * MEG), ffu, ffu_b, (int)(4 * MEG),
            ffd, ffd_b, (int)(4 * MEG), nullptr, nullptr, 0);
        cvt4_kernel<<<dim3(16384, 1), 256, 0, stream>>>(
            ctx, ctxb, 33554432, nullptr, nullptr, 0,
            nullptr, nullptr, 0, nullptr, nullptr, 0);

        // ---- self-attention ----
        adarms_kernel<<<4096, 256, 0, stream>>>(xf, n1w, mod3, normed);
        gemm256<0><<<dim3(12, 16), 512, 0, stream>>>(normed, saq_b, qkv, 1024, 3072, 0);
        attn_kernel<<<dim3(8, 16, 8), 256, 0, stream>>>(qkv, 3072, qkv + 1024, qkv + 2048, 3072, obuf, 512);
        gemm_bt<u16, u16, 1><<<dim3(8, 32), 256, 0, stream>>>(obuf, sao_b, nullptr, nullptr, xf, mod3, 4096, 1024, 1024, 1024, 0);

        // ---- cross-attention ----
        adarms_kernel<<<4096, 256, 0, stream>>>(xf, n2w, mod3 + 24576, normed);
        gemm_bt<u16, u16, 0><<<dim3(8, 32), 256, 0, stream>>>(normed, caq_b, qkv, nullptr, nullptr, nullptr, 4096, 1024, 1024, 1024, 0);
        gemm256<0><<<dim3(8, 64), 512, 0, stream>>>(ctxb, cakv_b, kvb, 2048, 2048, 0);
        attn_kernel<<<dim3(8, 16, 8), 256, 0, stream>>>(qkv, 1024, kvb, kvb + 1024, 2048, obuf, 2048);
        gemm_bt<u16, u16, 1><<<dim3(8, 32), 256, 0, stream>>>(obuf, cao_b, nullptr, nullptr, xf, mod3 + 24576, 4096, 1024, 1024, 1024, 0);

        // ---- SwiGLU MLP ----
        adarms_kernel<<<4096, 256, 0, stream>>>(xf, n3w, mod3 + 49152, normed);
        gemm256<0><<<dim3(16, 16), 512, 0, stream>>>(normed, ffg_b, kvb, 1024, 4096, 0);
        gemm256<2><<<dim3(16, 16), 512, 0, stream>>>(normed, ffu_b, kvb, 1024, 4096, 0);
        gemm_bt<u16, u16, 3><<<dim3(8, 32), 256, 0, stream>>>(kvb, ffd_b, nullptr, out, xf, mod3 + 49152, 4096, 1024, 4096, 1024, 0);
    } else {
        // ---- fallback: fp32-staging path ----
        adarms_kernel<<<4096, 256, 0, stream>>>(xf, n1w, mod3, normed);
        gemm_bt<u16, float, 0><<<dim3(8, 32), 256, 0, stream>>>(normed, saq, qkv, nullptr, nullptr, nullptr, 4096, 1024, 1024, 3072, 0);
        gemm_bt<u16, float, 0><<<dim3(8, 32), 256, 0, stream>>>(normed, sak, qkv, nullptr, nullptr, nullptr, 4096, 1024, 1024, 3072, 1024);
        gemm_bt<u16, float, 0><<<dim3(8, 32), 256, 0, stream>>>(normed, sav, qkv, nullptr, nullptr, nullptr, 4096, 1024, 1024, 3072, 2048);
        attn_kernel<<<dim3(8, 16, 8), 256, 0, stream>>>(qkv, 3072, qkv + 1024, qkv + 2048, 3072, obuf, 512);
        gemm_bt<u16, float, 1><<<dim3(8, 32), 256, 0, stream>>>(obuf, sao, nullptr, nullptr, xf, mod3, 4096, 1024, 1024, 1024, 0);

        adarms_kernel<<<4096, 256, 0, stream>>>(xf, n2w, mod3 + 24576, normed);
        gemm_bt<u16, float, 0><<<dim3(8, 32), 256, 0, stream>>>(normed, caq, qkv, nullptr, nullptr, nullptr, 4096, 1024, 1024, 1024, 0);
        gemm_bt<float, float, 0><<<dim3(8, 128), 256, 0, stream>>>(ctx, cak, kvb, nullptr, nullptr, nullptr, 16384, 1024, 2048, 2048, 0);
        gemm_bt<float, float, 0><<<dim3(8, 128), 256, 0, stream>>>(ctx, cav, kvb, nullptr, nullptr, nullptr, 16384, 1024, 2048, 2048, 1024);
        attn_kernel<<<dim3(8, 16, 8), 256, 0, stream>>>(qkv, 1024, kvb, kvb + 1024, 2048, obuf, 2048);
        gemm_bt<u16, float, 1><<<dim3(8, 32), 256, 0, stream>>>(obuf, cao, nullptr, nullptr, xf, mod3 + 24576, 4096, 1024, 1024, 1024, 0);

        adarms_kernel<<<4096, 256, 0, stream>>>(xf, n3w, mod3 + 49152, normed);
        gemm_bt<u16, float, 0><<<dim3(32, 32), 256, 0, stream>>>(normed, ffg, kvb, nullptr, nullptr, nullptr, 4096, 4096, 1024, 4096, 0);
        gemm_bt<u16, float, 2><<<dim3(32, 32), 256, 0, stream>>>(normed, ffu, kvb, nullptr, nullptr, nullptr, 4096, 4096, 1024, 4096, 0);
        gemm_bt<u16, float, 3><<<dim3(8, 32), 256, 0, stream>>>(kvb, ffd, nullptr, out, xf, mod3 + 49152, 4096, 1024, 4096, 1024, 0);
    }
}

// Round 3
// 969.693 us; speedup vs baseline: 1.5337x; 1.0058x over previous
//
#include <hip/hip_runtime.h>

typedef unsigned short u16;
typedef __bf16 v8bf __attribute__((ext_vector_type(8)));
typedef float  v4f  __attribute__((ext_vector_type(4)));

__device__ __forceinline__ float b2f(u16 h) { return __uint_as_float(((unsigned)h) << 16); }
__device__ __forceinline__ u16 f2b(float f) {
    unsigned u = __float_as_uint(f);
    unsigned r = (u + 0x7FFFu + ((u >> 16) & 1u)) >> 16;  // RNE
    return (u16)r;
}

// ---------------------------------------------------------------------------
// fp32 -> bf16 bulk conversion; 4 independent tensors per launch.
__global__ __launch_bounds__(256) void cvt4_kernel(
    const float* __restrict__ s0, u16* __restrict__ d0, int n0,
    const float* __restrict__ s1, u16* __restrict__ d1, int n1,
    const float* __restrict__ s2, u16* __restrict__ d2, int n2,
    const float* __restrict__ s3, u16* __restrict__ d3, int n3) {
    const float* s; u16* d; int n;
    switch (blockIdx.y) {
        case 0:  s = s0; d = d0; n = n0; break;
        case 1:  s = s1; d = d1; n = n1; break;
        case 2:  s = s2; d = d2; n = n2; break;
        default: s = s3; d = d3; n = n3; break;
    }
    int i = blockIdx.x * 256 + threadIdx.x;   // handles elements [8i, 8i+8)
    if (i * 8 < n) {
        float4 a = ((const float4*)s)[i * 2];
        float4 b = ((const float4*)s)[i * 2 + 1];
        ((ushort4*)d)[i * 2]     = make_ushort4(f2b(a.x), f2b(a.y), f2b(a.z), f2b(a.w));
        ((ushort4*)d)[i * 2 + 1] = make_ushort4(f2b(b.x), f2b(b.y), f2b(b.z), f2b(b.w));
    }
}

// ---------------------------------------------------------------------------
// ffg/ffu row-interleave + bf16 convert: W'[2j+o] = (o? ffu : ffg)[j]
__global__ __launch_bounds__(256) void cvt_ilv_kernel(
    const float* __restrict__ g, const float* __restrict__ u, u16* __restrict__ d) {
    const int o = blockIdx.y;
    const float* s = o ? u : g;
    int e = (blockIdx.x * 256 + threadIdx.x) * 8;   // 4096*1024 elems
    int row = e >> 10, col = e & 1023;
    float4 a = *(const float4*)(s + e);
    float4 b = *(const float4*)(s + e + 4);
    u16* dst = d + ((size_t)((row << 1) | o) << 10) + col;
    *(ushort4*)(dst)     = make_ushort4(f2b(a.x), f2b(a.y), f2b(a.z), f2b(a.w));
    *(ushort4*)(dst + 4) = make_ushort4(f2b(b.x), f2b(b.y), f2b(b.z), f2b(b.w));
}

// ---------------------------------------------------------------------------
// mod3[p][b][j] = sum_k cond[b][k]*mw_p[j][k] + mb_p[j]
// One wave per (p, j): reads the 4KB weight row ONCE, dots against all 8 b.
__global__ __launch_bounds__(256) void mod_kernel(
    const float* __restrict__ cond,
    const float* __restrict__ mw0, const float* __restrict__ mb0,
    const float* __restrict__ mw1, const float* __restrict__ mb1,
    const float* __restrict__ mw2, const float* __restrict__ mb2,
    float* __restrict__ mod3) {
    const int tid = threadIdx.x, wave = tid >> 6, lane = tid & 63;
    int job = blockIdx.x * 4 + wave;  // 9216 jobs = 3 * 3072
    int p = job / 3072, j = job % 3072;
    const float* mw = p == 0 ? mw0 : (p == 1 ? mw1 : mw2);
    const float* mb = p == 0 ? mb0 : (p == 1 ? mb1 : mb2);
    const float4* wr = (const float4*)(mw + (size_t)j * 1024);
    float4 wv[4];
#pragma unroll
    for (int t = 0; t < 4; t++) wv[t] = wr[lane + t * 64];
    float s[8];
#pragma unroll
    for (int b = 0; b < 8; b++) {
        const float4* c = (const float4*)(cond + b * 1024);
        float a = 0.f;
#pragma unroll
        for (int t = 0; t < 4; t++) {
            float4 cv = c[lane + t * 64];
            a += cv.x * wv[t].x + cv.y * wv[t].y + cv.z * wv[t].z + cv.w * wv[t].w;
        }
#pragma unroll
        for (int o = 32; o > 0; o >>= 1) a += __shfl_xor(a, o, 64);
        s[b] = a;
    }
    if (lane == 0) {
        float base = mb[j];
#pragma unroll
        for (int b = 0; b < 8; b++) mod3[(size_t)p * 24576 + b * 3072 + j] = s[b] + base;
    }
}

// ---------------------------------------------------------------------------
// AdaRMS: bf16 out = x*rsqrt(mean(x^2)+eps)*w*(1+scale)+shift
__global__ __launch_bounds__(256) void adarms_kernel(
    const float* __restrict__ Xf, const float* __restrict__ w,
    const float* __restrict__ mod, u16* __restrict__ Out) {
    __shared__ float red[4];
    const int row = blockIdx.x, tid = threadIdx.x;
    const int bidx = row >> 9;
    const float* x = Xf + (size_t)row * 1024;
    float4 v = *(const float4*)(x + tid * 4);
    float s = v.x * v.x + v.y * v.y + v.z * v.z + v.w * v.w;
#pragma unroll
    for (int o = 32; o > 0; o >>= 1) s += __shfl_xor(s, o, 64);
    if ((tid & 63) == 0) red[tid >> 6] = s;
    __syncthreads();
    float tot = red[0] + red[1] + red[2] + red[3];
    float norm = 1.0f / sqrtf(tot * (1.f / 1024.f) + 1e-6f);
    const float* mo = mod + (size_t)bidx * 3072;
    int d = tid * 4;
    float4 wv = *(const float4*)(w + d);
    const float xv[4] = {v.x, v.y, v.z, v.w};
    const float wa[4] = {wv.x, wv.y, wv.z, wv.w};
    u16 o4[4];
#pragma unroll
    for (int t = 0; t < 4; t++) {
        float sc = mo[d + t], sh = mo[1024 + d + t];
        o4[t] = f2b(xv[t] * norm * wa[t] * (1.f + sc) + sh);
    }
    *(ushort4*)(Out + (size_t)row * 1024 + d) = make_ushort4(o4[0], o4[1], o4[2], o4[3]);
}

// ---------------------------------------------------------------------------
// Staging 128 rows x 32 k into LDS as bf16 (128^2 GEMM).
template <typename T>
__device__ __forceinline__ void stage_tile(const T* __restrict__ G, int ldg, int row0,
                                           int k0, u16* lds, int tid) {
    if constexpr (sizeof(T) == 2) {
        const int wave = tid >> 6, lane = tid & 63;
        const int r4 = lane >> 2, c8 = (lane & 3) * 8;
#pragma unroll
        for (int i = 0; i < 2; i++) {
            int row = wave * 32 + i * 16;
            __builtin_amdgcn_global_load_lds(
                (__attribute__((address_space(1))) void*)((const u16*)G + (size_t)(row0 + row + r4) * ldg + k0 + c8),
                (__attribute__((address_space(3))) void*)(&lds[row * 32]), 16, 0, 0);
        }
    } else {
        const int row = tid >> 1, col = (tid & 1) * 16;
        const float* src = (const float*)G + (size_t)(row0 + row) * ldg + k0 + col;
        float4 f0 = *(const float4*)(src);
        float4 f1 = *(const float4*)(src + 4);
        float4 f2 = *(const float4*)(src + 8);
        float4 f3 = *(const float4*)(src + 12);
        ushort4* dst = (ushort4*)(&lds[row * 32 + col]);
        dst[0] = make_ushort4(f2b(f0.x), f2b(f0.y), f2b(f0.z), f2b(f0.w));
        dst[1] = make_ushort4(f2b(f1.x), f2b(f1.y), f2b(f1.z), f2b(f1.w));
        dst[2] = make_ushort4(f2b(f2.x), f2b(f2.y), f2b(f2.z), f2b(f2.w));
        dst[3] = make_ushort4(f2b(f3.x), f2b(f3.y), f2b(f3.z), f2b(f3.w));
    }
}

// ---------------------------------------------------------------------------
// 128x128 GEMM (N=1024 shapes + fp32 fallback). C = A @ Bw^T.
template <typename TA, typename TB, int MODE>
__global__ __launch_bounds__(256) void gemm_bt(
    const TA* __restrict__ A, const TB* __restrict__ Bw,
    u16* __restrict__ Cb, float* __restrict__ Cf,
    float* __restrict__ Xf, const float* __restrict__ mod,
    int M, int N, int K, int ldc, int coff) {
    __shared__ u16 As[128 * 32];
    __shared__ u16 Bs[128 * 32];
    const int tid = threadIdx.x;
    const int wave = tid >> 6, lane = tid & 63;
    const int gx = gridDim.x, nwg = gx * gridDim.y;
    int bid = blockIdx.y * gx + blockIdx.x;
    bid = (bid & 7) * (nwg >> 3) + (bid >> 3);
    const int m0 = (bid / gx) * 128, n0 = (bid % gx) * 128;
    const int wm = (wave >> 1) * 64, wn = (wave & 1) * 64;
    const int kq = lane >> 4, rr = lane & 15;

    v4f acc[4][4];
#pragma unroll
    for (int i = 0; i < 4; i++)
#pragma unroll
        for (int j = 0; j < 4; j++) acc[i][j] = (v4f){0.f, 0.f, 0.f, 0.f};

    for (int k0 = 0; k0 < K; k0 += 32) {
        __syncthreads();
        stage_tile<TA>(A, K, m0, k0, As, tid);
        stage_tile<TB>(Bw, K, n0, k0, Bs, tid);
        __syncthreads();
        v8bf a[4], b[4];
#pragma unroll
        for (int i = 0; i < 4; i++) a[i] = *(const v8bf*)(&As[(wm + i * 16 + rr) * 32 + kq * 8]);
#pragma unroll
        for (int j = 0; j < 4; j++) b[j] = *(const v8bf*)(&Bs[(wn + j * 16 + rr) * 32 + kq * 8]);
#pragma unroll
        for (int i = 0; i < 4; i++)
#pragma unroll
            for (int j = 0; j < 4; j++)
                acc[i][j] = __builtin_amdgcn_mfma_f32_16x16x32_bf16(a[i], b[j], acc[i][j], 0, 0, 0);
    }

    const int quad = lane >> 4, cl = lane & 15;
#pragma unroll
    for (int i = 0; i < 4; i++)
#pragma unroll
        for (int j = 0; j < 4; j++)
#pragma unroll
            for (int r = 0; r < 4; r++) {
                int row = m0 + wm + i * 16 + quad * 4 + r;
                int col = n0 + wn + j * 16 + cl;
                size_t idx = (size_t)row * ldc + coff + col;
                float v = acc[i][j][r];
                if constexpr (MODE == 0) {
                    Cb[idx] = f2b(v);
                } else if constexpr (MODE == 1) {
                    float g = mod[(row >> 9) * 3072 + 2048 + col];
                    Xf[(size_t)row * 1024 + col] += g * v;
                } else if constexpr (MODE == 2) {
                    float gv = b2f(Cb[idx]);
                    float s = gv / (1.f + __expf(-gv));
                    Cb[idx] = f2b(s * v);
                } else {
                    float g = mod[(row >> 9) * 3072 + 2048 + col];
                    Cf[idx] = Xf[(size_t)row * 1024 + col] + g * v;
                }
            }
}

// ---------------------------------------------------------------------------
// 256x256 / BK=64 8-wave GEMM, register-pipelined 4-phase schedule:
// ONE raw barrier + ONE vmcnt wait per K-tile; each phase issues the next
// phase's ds_reads BEFORE its MFMA burst (sched_barrier-fenced) so LDS runs
// under the MFMA shadow. Next-tile DMA staged at phase A (~3-phase cover).
// LDS: flat [256 rows][64 k], 16B chunk c stored at c ^ (row&7); staged with
// the inverse permutation on the per-lane GLOBAL address (linear DMA dest).
// MODE 0: Cb = bf16(acc)
// MODE 5: rows of Bw are interleaved gate/up; even col = gate, odd = up;
//         Cb[row][col>>1] = bf16(silu(gate)*up)  (SwiGLU fused epilogue)
__device__ __forceinline__ void stage128(const u16* __restrict__ G, int ldg,
                                         int grow0, int k0, u16* lds,
                                         int w, int lane) {
    const int co = ((lane & 7) ^ (lane >> 3)) * 8;
#pragma unroll
    for (int q = 0; q < 2; q++) {
        int s = w * 2 + q;   // 1KB slot: rows s*8 .. s*8+7
        __builtin_amdgcn_global_load_lds(
            (__attribute__((address_space(1))) void*)(G + (size_t)(grow0 + s * 8 + (lane >> 3)) * ldg + k0 + co),
            (__attribute__((address_space(3))) void*)(lds + s * 512), 16, 0, 0);
    }
}

__device__ __forceinline__ v8bf fragv2(const u16* lds, int row, int c) {
    return *(const v8bf*)(lds + row * 64 + ((c ^ (row & 7)) << 3));
}

template <int MODE>
__global__ __launch_bounds__(512, 2) void gemm256(
    const u16* __restrict__ A, const u16* __restrict__ Bw,
    u16* __restrict__ Cb, int K, int ldc, int coff) {
    __shared__ u16 As[2][16384];   // [buf][256 rows * 64 k]
    __shared__ u16 Bs[2][16384];
    const int tid = threadIdx.x, w = tid >> 6, lane = tid & 63;
    const int gx = gridDim.x, nwg = gx * gridDim.y;
    int bid = blockIdx.y * gx + blockIdx.x;
    bid = (bid & 7) * (nwg >> 3) + (bid >> 3);      // T1 (nwg % 8 == 0)
    const int n0 = (bid % gx) * 256, m0 = (bid / gx) * 256;
    const int wm = w >> 2, wn = w & 3;              // 2 x 4 wave grid
    const int rr = lane & 15, kq = lane >> 4;

    v4f acc[8][4];
#pragma unroll
    for (int i = 0; i < 8; i++)
#pragma unroll
        for (int j = 0; j < 4; j++) acc[i][j] = (v4f){0.f, 0.f, 0.f, 0.f};

    const int nt = K >> 6;
    // prologue: stage tile 0
    stage128(A, K, m0, 0, &As[0][0], w, lane);
    stage128(A, K, m0 + 128, 0, &As[0][8192], w, lane);
    stage128(Bw, K, n0, 0, &Bs[0][0], w, lane);
    stage128(Bw, K, n0 + 128, 0, &Bs[0][8192], w, lane);
    asm volatile("s_waitcnt vmcnt(0)" ::: "memory");
    __builtin_amdgcn_s_barrier();

    for (int t = 0; t < nt; ++t) {
        const u16* At = &As[t & 1][0];
        const u16* Bt = &Bs[t & 1][0];
        u16* Ao = &As[(t + 1) & 1][0];
        u16* Bo = &Bs[(t + 1) & 1][0];
        const int k1 = (t + 1) << 6;
        const bool st = (t + 1 < nt);
        v8bf b1[4], b2[4], a1[4], a2[4], a3[4], a4[4];

        // ---- phase A: stage next tile; read set1; prefetch set2; MFMA set1
        if (st) {
            stage128(A, K, m0, k1, Ao, w, lane);
            stage128(A, K, m0 + 128, k1, &Ao[8192], w, lane);
            stage128(Bw, K, n0, k1, Bo, w, lane);
            stage128(Bw, K, n0 + 128, k1, &Bo[8192], w, lane);
        }
#pragma unroll
        for (int j = 0; j < 4; j++) b1[j] = fragv2(Bt, wn * 64 + j * 16 + rr, kq);
#pragma unroll
        for (int i = 0; i < 4; i++) a1[i] = fragv2(At, wm * 128 + i * 16 + rr, kq);
        asm volatile("s_waitcnt lgkmcnt(0)" ::: "memory");
        __builtin_amdgcn_sched_barrier(0);
#pragma unroll
        for (int i = 0; i < 4; i++) a2[i] = fragv2(At, wm * 128 + 64 + i * 16 + rr, kq);
        __builtin_amdgcn_sched_barrier(0);
        __builtin_amdgcn_s_setprio(1);
#pragma unroll
        for (int i = 0; i < 4; i++)
#pragma unroll
            for (int j = 0; j < 4; j++)
                acc[i][j] = __builtin_amdgcn_mfma_f32_16x16x32_bf16(a1[i], b1[j], acc[i][j], 0, 0, 0);
        __builtin_amdgcn_s_setprio(0);

        // ---- phase B: prefetch khalf1 B+A(mi0-3); MFMA set2
        asm volatile("s_waitcnt lgkmcnt(0)" ::: "memory");
        __builtin_amdgcn_sched_barrier(0);
#pragma unroll
        for (int j = 0; j < 4; j++) b2[j] = fragv2(Bt, wn * 64 + j * 16 + rr, 4 + kq);
#pragma unroll
        for (int i = 0; i < 4; i++) a3[i] = fragv2(At, wm * 128 + i * 16 + rr, 4 + kq);
        __builtin_amdgcn_sched_barrier(0);
        __builtin_amdgcn_s_setprio(1);
#pragma unroll
        for (int i = 0; i < 4; i++)
#pragma unroll
            for (int j = 0; j < 4; j++)
                acc[4 + i][j] = __builtin_amdgcn_mfma_f32_16x16x32_bf16(a2[i], b1[j], acc[4 + i][j], 0, 0, 0);
        __builtin_amdgcn_s_setprio(0);

        // ---- phase C: prefetch A(mi4-7) khalf1; MFMA set1'
        asm volatile("s_waitcnt lgkmcnt(0)" ::: "memory");
        __builtin_amdgcn_sched_barrier(0);
#pragma unroll
        for (int i = 0; i < 4; i++) a4[i] = fragv2(At, wm * 128 + 64 + i * 16 + rr, 4 + kq);
        __builtin_amdgcn_sched_barrier(0);
        __builtin_amdgcn_s_setprio(1);
#pragma unroll
        for (int i = 0; i < 4; i++)
#pragma unroll
            for (int j = 0; j < 4; j++)
                acc[i][j] = __builtin_amdgcn_mfma_f32_16x16x32_bf16(a3[i], b2[j], acc[i][j], 0, 0, 0);
        __builtin_amdgcn_s_setprio(0);

        // ---- phase D: MFMA set2'
        asm volatile("s_waitcnt lgkmcnt(0)" ::: "memory");
        __builtin_amdgcn_sched_barrier(0);
        __builtin_amdgcn_s_setprio(1);
#pragma unroll
        for (int i = 0; i < 4; i++)
#pragma unroll
            for (int j = 0; j < 4; j++)
                acc[4 + i][j] = __builtin_amdgcn_mfma_f32_16x16x32_bf16(a4[i], b2[j], acc[4 + i][j], 0, 0, 0);
        __builtin_amdgcn_s_setprio(0);

        if (st) asm volatile("s_waitcnt vmcnt(0)" ::: "memory");  // issued ~3 phases ago
        __builtin_amdgcn_s_barrier();
    }

    // ---- epilogue ----
    const int quad = lane >> 4, cl = lane & 15;
#pragma unroll
    for (int i = 0; i < 8; i++)
#pragma unroll
        for (int j = 0; j < 4; j++)
#pragma unroll
            for (int r = 0; r < 4; r++) {
                int row = m0 + wm * 128 + i * 16 + quad * 4 + r;
                int col = n0 + wn * 64 + j * 16 + cl;
                float v = acc[i][j][r];
                if constexpr (MODE == 0) {
                    Cb[(size_t)row * ldc + coff + col] = f2b(v);
                } else {
                    float o = __shfl_xor(v, 1, 64);
                    if (!(lane & 1)) {
                        float h = (v / (1.f + __expf(-v))) * o;
                        Cb[(size_t)row * ldc + (col >> 1)] = f2b(h);
                    }
                }
            }
}

// ---------------------------------------------------------------------------
// MFMA flash attention (unchanged, verified).
#define ATTN_SCL 0.125f
__global__ __launch_bounds__(256) void attn_kernel(
    const u16* __restrict__ Q, int ldq,
    const u16* __restrict__ Kp, const u16* __restrict__ Vp, int ldkv,
    u16* __restrict__ Out, int S) {
    __shared__ u16 Ks[64 * 64];
    __shared__ u16 Qs[64 * 64];
    __shared__ u16 Vs[64 * 66];
    __shared__ u16 Ps[4][16 * 72];
    const int tid = threadIdx.x, wave = tid >> 6, lane = tid & 63;
    const int b = blockIdx.z, h = blockIdx.y, q0 = blockIdx.x * 64;
    const int Nq = 512;
    const int rr = lane & 15, quad = lane >> 4;
    const int drow = lane >> 3;
    const int dchunk = (lane & 7) ^ drow;

#pragma unroll
    for (int i = 0; i < 2; i++) {
        int r = wave * 16 + i * 8 + drow;
        __builtin_amdgcn_global_load_lds(
            (__attribute__((address_space(1))) void*)(Q + (size_t)(b * Nq + q0 + r) * ldq + h * 64 + dchunk * 8),
            (__attribute__((address_space(3))) void*)(&Qs[(wave * 16 + i * 8) * 64]), 16, 0, 0);
    }
    __syncthreads();

    v8bf qf[2];
#pragma unroll
    for (int h2 = 0; h2 < 2; h2++)
        qf[h2] = *(const v8bf*)(&Qs[(wave * 16 + rr) * 64 + (((quad + 4 * h2) ^ (rr & 7)) * 8)]);

    v4f Oa[4];
#pragma unroll
    for (int t = 0; t < 4; t++) Oa[t] = (v4f){0.f, 0.f, 0.f, 0.f};
    float m = -3e38f, l = 0.f;

    for (int s0 = 0; s0 < S; s0 += 64) {
        __syncthreads();
#pragma unroll
        for (int i = 0; i < 2; i++) {
            int r = wave * 16 + i * 8 + drow;
            __builtin_amdgcn_global_load_lds(
                (__attribute__((address_space(1))) void*)(Kp + (size_t)(b * S + s0 + r) * ldkv + h * 64 + dchunk * 8),
                (__attribute__((address_space(3))) void*)(&Ks[(wave * 16 + i * 8) * 64]), 16, 0, 0);
        }
        {
            int vr = tid >> 2, c0 = (tid & 3) * 16;
            const u16* src = Vp + (size_t)(b * S + s0 + vr) * ldkv + h * 64 + c0;
            uint4 u0 = *(const uint4*)(src);
            uint4 u1 = *(const uint4*)(src + 8);
            unsigned* dst = (unsigned*)(&Vs[vr * 66 + c0]);
            dst[0] = u0.x; dst[1] = u0.y; dst[2] = u0.z; dst[3] = u0.w;
            dst[4] = u1.x; dst[5] = u1.y; dst[6] = u1.z; dst[7] = u1.w;
        }
        __syncthreads();

        v4f Sf[4];
#pragma unroll
        for (int t = 0; t < 4; t++) Sf[t] = (v4f){0.f, 0.f, 0.f, 0.f};
#pragma unroll
        for (int t = 0; t < 4; t++)
#pragma unroll
            for (int h2 = 0; h2 < 2; h2++) {
                v8bf kf = *(const v8bf*)(&Ks[(16 * t + rr) * 64 + (((quad + 4 * h2) ^ (rr & 7)) * 8)]);
                Sf[t] = __builtin_amdgcn_mfma_f32_16x16x32_bf16(kf, qf[h2], Sf[t], 0, 0, 0);
            }
        float mx = -3e38f;
#pragma unroll
        for (int t = 0; t < 4; t++)
#pragma unroll
            for (int r = 0; r < 4; r++) {
                float v = Sf[t][r] * ATTN_SCL;
                Sf[t][r] = v;
                mx = fmaxf(mx, v);
            }
        mx = fmaxf(mx, __shfl_xor(mx, 16, 64));
        mx = fmaxf(mx, __shfl_xor(mx, 32, 64));
        float mn = fmaxf(m, mx);
        float alpha = __expf(m - mn);
        float su = 0.f;
#pragma unroll
        for (int t = 0; t < 4; t++)
#pragma unroll
            for (int r = 0; r < 4; r++) {
                float p = __expf(Sf[t][r] - mn);
                Sf[t][r] = p;
                su += p;
            }
        su += __shfl_xor(su, 16, 64);
        su += __shfl_xor(su, 32, 64);
        l = l * alpha + su;
        m = mn;
#pragma unroll
        for (int t = 0; t < 4; t++)
#pragma unroll
            for (int r = 0; r < 4; r++) Oa[t][r] *= alpha;
#pragma unroll
        for (int t = 0; t < 4; t++) {
            ushort4 pw = make_ushort4(f2b(Sf[t][0]), f2b(Sf[t][1]), f2b(Sf[t][2]), f2b(Sf[t][3]));
            *(ushort4*)(&Ps[wave][rr * 72 + 16 * t + 4 * quad]) = pw;
        }
        v8bf pf[2];
#pragma unroll
        for (int h2 = 0; h2 < 2; h2++)
            pf[h2] = *(const v8bf*)(&Ps[wave][rr * 72 + quad * 8 + 32 * h2]);
#pragma unroll
        for (int t = 0; t < 4; t++)
#pragma unroll
            for (int h2 = 0; h2 < 2; h2++) {
                union { v8bf v; u16 e[8]; } vf;
#pragma unroll
                for (int j = 0; j < 8; j++)
                    vf.e[j] = Vs[(quad * 8 + j + 32 * h2) * 66 + 16 * t + rr];
                Oa[t] = __builtin_amdgcn_mfma_f32_16x16x32_bf16(vf.v, pf[h2], Oa[t], 0, 0, 0);
            }
    }
    float inv = 1.f / l;
#pragma unroll
    for (int t = 0; t < 4; t++) {
        ushort4 ow = make_ushort4(f2b(Oa[t][0] * inv), f2b(Oa[t][1] * inv),
                                  f2b(Oa[t][2] * inv), f2b(Oa[t][3] * inv));
        *(ushort4*)(&Ps[wave][rr * 72 + 16 * t + 4 * quad]) = ow;
    }
#pragma unroll
    for (int j = 0; j < 2; j++) {
        int idx = j * 64 + lane;
        int ql = idx >> 3, c = (idx & 7) * 8;
        uint4 u = *(const uint4*)(&Ps[wave][ql * 72 + c]);
        *(uint4*)(Out + (size_t)(b * Nq + q0 + wave * 16 + ql) * 1024 + h * 64 + c) = u;
    }
}

// ---------------------------------------------------------------------------
extern "C" void kernel_launch(void* const* d_in, const int* in_sizes, int n_in,
                              void* d_out, int out_size, void* d_ws, size_t ws_size,
                              hipStream_t stream) {
    (void)in_sizes; (void)n_in; (void)out_size;
    const float* x    = (const float*)d_in[0];
    const float* ctx  = (const float*)d_in[1];
    const float* cond = (const float*)d_in[2];
    const float* n1w = (const float*)d_in[3];  const float* n1mw = (const float*)d_in[4];  const float* n1mb = (const float*)d_in[5];
    const float* n2w = (const float*)d_in[6];  const float* n2mw = (const float*)d_in[7];  const float* n2mb = (const float*)d_in[8];
    const float* n3w = (const float*)d_in[9];  const float* n3mw = (const float*)d_in[10]; const float* n3mb = (const float*)d_in[11];
    const float* saq = (const float*)d_in[12]; const float* sak = (const float*)d_in[13];
    const float* sav = (const float*)d_in[14]; const float* sao = (const float*)d_in[15];
    const float* caq = (const float*)d_in[16]; const float* cak = (const float*)d_in[17];
    const float* cav = (const float*)d_in[18]; const float* cao = (const float*)d_in[19];
    const float* ffg = (const float*)d_in[20]; const float* ffu = (const float*)d_in[21];
    const float* ffd = (const float*)d_in[22];
    float* out = (float*)d_out;

    char* ws = (char*)d_ws;
    size_t off = 0;
    auto alloc = [&](size_t bytes) { void* p = ws + off; off += (bytes + 255) & ~(size_t)255; return p; };
    float* xf   = (float*)alloc((size_t)4194304 * 4);
    u16* normed = (u16*)alloc((size_t)4194304 * 2);
    u16* qkv    = (u16*)alloc((size_t)12582912 * 2);
    u16* kvb    = (u16*)alloc((size_t)33554432 * 2);
    u16* obuf   = (u16*)alloc((size_t)4194304 * 2);
    float* mod3 = (float*)alloc((size_t)73728 * 4);
    const size_t MEG = 1048576;
    u16* ctxb = (u16*)alloc((size_t)33554432 * 2);
    u16* wb   = (u16*)alloc((size_t)22 * MEG * 2);
    u16* saq_b = wb;            u16* sak_b = wb + 1 * MEG;  u16* sav_b = wb + 2 * MEG;
    u16* sao_b = wb + 3 * MEG;  u16* caq_b = wb + 4 * MEG;
    u16* cakv_b = wb + 5 * MEG;
    u16* cak_b = wb + 5 * MEG;  u16* cav_b = wb + 7 * MEG;
    u16* cao_b = wb + 9 * MEG;
    u16* ffgu_b = wb + 10 * MEG;   // interleaved gate/up [8192][1024]
    u16* ffd_b  = wb + 18 * MEG;
    const bool CVT = (ws_size >= off);

    hipMemcpyAsync(xf, x, (size_t)4194304 * 4, hipMemcpyDeviceToDevice, stream);
    mod_kernel<<<2304, 256, 0, stream>>>(cond, n1mw, n1mb, n2mw, n2mb, n3mw, n3mb, mod3);

    if (CVT) {
        cvt4_kernel<<<dim3(512, 4), 256, 0, stream>>>(
            saq, saq_b, (int)MEG, sak, sak_b, (int)MEG,
            sav, sav_b, (int)MEG, sao, sao_b, (int)MEG);
        cvt4_kernel<<<dim3(1024, 4), 256, 0, stream>>>(
            cak, cak_b, (int)(2 * MEG), cav, cav_b, (int)(2 * MEG),
            caq, caq_b, (int)MEG, cao, cao_b, (int)MEG);
        cvt_ilv_kernel<<<dim3(2048, 2), 256, 0, stream>>>(ffg, ffu, ffgu_b);
        cvt4_kernel<<<dim3(16384, 2), 256, 0, stream>>>(
            ctx, ctxb, 33554432, ffd, ffd_b, (int)(4 * MEG),
            nullptr, nullptr, 0, nullptr, nullptr, 0);

        // ---- self-attention ----
        adarms_kernel<<<4096, 256, 0, stream>>>(xf, n1w, mod3, normed);
        gemm256<0><<<dim3(12, 16), 512, 0, stream>>>(normed, saq_b, qkv, 1024, 3072, 0);
        attn_kernel<<<dim3(8, 16, 8), 256, 0, stream>>>(qkv, 3072, qkv + 1024, qkv + 2048, 3072, obuf, 512);
        gemm_bt<u16, u16, 1><<<dim3(8, 32), 256, 0, stream>>>(obuf, sao_b, nullptr, nullptr, xf, mod3, 4096, 1024, 1024, 1024, 0);

        // ---- cross-attention ----
        adarms_kernel<<<4096, 256, 0, stream>>>(xf, n2w, mod3 + 24576, normed);
        gemm_bt<u16, u16, 0><<<dim3(8, 32), 256, 0, stream>>>(normed, caq_b, qkv, nullptr, nullptr, nullptr, 4096, 1024, 1024, 1024, 0);
        gemm256<0><<<dim3(8, 64), 512, 0, stream>>>(ctxb, cakv_b, kvb, 2048, 2048, 0);
        attn_kernel<<<dim3(8, 16, 8), 256, 0, stream>>>(qkv, 1024, kvb, kvb + 1024, 2048, obuf, 2048);
        gemm_bt<u16, u16, 1><<<dim3(8, 32), 256, 0, stream>>>(obuf, cao_b, nullptr, nullptr, xf, mod3 + 24576, 4096, 1024, 1024, 1024, 0);

        // ---- SwiGLU MLP: one N=8192 GEMM with fused silu-mul epilogue ----
        adarms_kernel<<<4096, 256, 0, stream>>>(xf, n3w, mod3 + 49152, normed);
        gemm256<5><<<dim3(32, 16), 512, 0, stream>>>(normed, ffgu_b, kvb, 1024, 4096, 0);
        gemm_bt<u16, u16, 3><<<dim3(8, 32), 256, 0, stream>>>(kvb, ffd_b, nullptr, out, xf, mod3 + 49152, 4096, 1024, 4096, 1024, 0);
    } else {
        // ---- fallback: fp32-staging path ----
        adarms_kernel<<<4096, 256, 0, stream>>>(xf, n1w, mod3, normed);
        gemm_bt<u16, float, 0><<<dim3(8, 32), 256, 0, stream>>>(normed, saq, qkv, nullptr, nullptr, nullptr, 4096, 1024, 1024, 3072, 0);
        gemm_bt<u16, float, 0><<<dim3(8, 32), 256, 0, stream>>>(normed, sak, qkv, nullptr, nullptr, nullptr, 4096, 1024, 1024, 3072, 1024);
        gemm_bt<u16, float, 0><<<dim3(8, 32), 256, 0, stream>>>(normed, sav, qkv, nullptr, nullptr, nullptr, 4096, 1024, 1024, 3072, 2048);
        attn_kernel<<<dim3(8, 16, 8), 256, 0, stream>>>(qkv, 3072, qkv + 1024, qkv + 2048, 3072, obuf, 512);
        gemm_bt<u16, float, 1><<<dim3(8, 32), 256, 0, stream>>>(obuf, sao, nullptr, nullptr, xf, mod3, 4096, 1024, 1024, 1024, 0);

        adarms_kernel<<<4096, 256, 0, stream>>>(xf, n2w, mod3 + 24576, normed);
        gemm_bt<u16, float, 0><<<dim3(8, 32), 256, 0, stream>>>(normed, caq, qkv, nullptr, nullptr, nullptr, 4096, 1024, 1024, 1024, 0);
        gemm_bt<float, float, 0><<<dim3(8, 128), 256, 0, stream>>>(ctx, cak, kvb, nullptr, nullptr, nullptr, 16384, 1024, 2048, 2048, 0);
        gemm_bt<float, float, 0><<<dim3(8, 128), 256, 0, stream>>>(ctx, cav, kvb, nullptr, nullptr, nullptr, 16384, 1024, 2048, 2048, 1024);
        attn_kernel<<<dim3(8, 16, 8), 256, 0, stream>>>(qkv, 1024, kvb, kvb + 1024, 2048, obuf, 2048);
        gemm_bt<u16, float, 1><<<dim3(8, 32), 256, 0, stream>>>(obuf, cao, nullptr, nullptr, xf, mod3 + 24576, 4096, 1024, 1024, 1024, 0);

        adarms_kernel<<<4096, 256, 0, stream>>>(xf, n3w, mod3 + 49152, normed);
        gemm_bt<u16, float, 0><<<dim3(32, 32), 256, 0, stream>>>(normed, ffg, kvb, nullptr, nullptr, nullptr, 4096, 4096, 1024, 4096, 0);
        gemm_bt<u16, float, 2><<<dim3(32, 32), 256, 0, stream>>>(normed, ffu, kvb, nullptr, nullptr, nullptr, 4096, 4096, 1024, 4096, 0);
        gemm_bt<u16, float, 3><<<dim3(8, 32), 256, 0, stream>>>(kvb, ffd, nullptr, out, xf, mod3 + 49152, 4096, 1024, 4096, 1024, 0);
    }
}

// Round 4
// 928.176 us; speedup vs baseline: 1.6023x; 1.0447x over previous
//
#include <hip/hip_runtime.h>

typedef unsigned short u16;
typedef __bf16 v8bf __attribute__((ext_vector_type(8)));
typedef float  v4f  __attribute__((ext_vector_type(4)));

__device__ __forceinline__ float b2f(u16 h) { return __uint_as_float(((unsigned)h) << 16); }
__device__ __forceinline__ u16 f2b(float f) {
    unsigned u = __float_as_uint(f);
    unsigned r = (u + 0x7FFFu + ((u >> 16) & 1u)) >> 16;  // RNE
    return (u16)r;
}

// ---------------------------------------------------------------------------
// fp32 -> bf16 bulk conversion; 4 independent tensors per launch.
__global__ __launch_bounds__(256) void cvt4_kernel(
    const float* __restrict__ s0, u16* __restrict__ d0, int n0,
    const float* __restrict__ s1, u16* __restrict__ d1, int n1,
    const float* __restrict__ s2, u16* __restrict__ d2, int n2,
    const float* __restrict__ s3, u16* __restrict__ d3, int n3) {
    const float* s; u16* d; int n;
    switch (blockIdx.y) {
        case 0:  s = s0; d = d0; n = n0; break;
        case 1:  s = s1; d = d1; n = n1; break;
        case 2:  s = s2; d = d2; n = n2; break;
        default: s = s3; d = d3; n = n3; break;
    }
    int i = blockIdx.x * 256 + threadIdx.x;   // handles elements [8i, 8i+8)
    if (i * 8 < n) {
        float4 a = ((const float4*)s)[i * 2];
        float4 b = ((const float4*)s)[i * 2 + 1];
        ((ushort4*)d)[i * 2]     = make_ushort4(f2b(a.x), f2b(a.y), f2b(a.z), f2b(a.w));
        ((ushort4*)d)[i * 2 + 1] = make_ushort4(f2b(b.x), f2b(b.y), f2b(b.z), f2b(b.w));
    }
}

// ---------------------------------------------------------------------------
// ffg/ffu row-interleave + bf16 convert: W'[2j+o] = (o? ffu : ffg)[j]
__global__ __launch_bounds__(256) void cvt_ilv_kernel(
    const float* __restrict__ g, const float* __restrict__ u, u16* __restrict__ d) {
    const int o = blockIdx.y;
    const float* s = o ? u : g;
    int e = (blockIdx.x * 256 + threadIdx.x) * 8;   // 4096*1024 elems
    int row = e >> 10, col = e & 1023;
    float4 a = *(const float4*)(s + e);
    float4 b = *(const float4*)(s + e + 4);
    u16* dst = d + ((size_t)((row << 1) | o) << 10) + col;
    *(ushort4*)(dst)     = make_ushort4(f2b(a.x), f2b(a.y), f2b(a.z), f2b(a.w));
    *(ushort4*)(dst + 4) = make_ushort4(f2b(b.x), f2b(b.y), f2b(b.z), f2b(b.w));
}

// ---------------------------------------------------------------------------
// mod3[p][b][j] = sum_k cond[b][k]*mw_p[j][k] + mb_p[j]
// One wave per (p, j): reads the 4KB weight row ONCE, dots against all 8 b.
__global__ __launch_bounds__(256) void mod_kernel(
    const float* __restrict__ cond,
    const float* __restrict__ mw0, const float* __restrict__ mb0,
    const float* __restrict__ mw1, const float* __restrict__ mb1,
    const float* __restrict__ mw2, const float* __restrict__ mb2,
    float* __restrict__ mod3) {
    const int tid = threadIdx.x, wave = tid >> 6, lane = tid & 63;
    int job = blockIdx.x * 4 + wave;  // 9216 jobs = 3 * 3072
    int p = job / 3072, j = job % 3072;
    const float* mw = p == 0 ? mw0 : (p == 1 ? mw1 : mw2);
    const float* mb = p == 0 ? mb0 : (p == 1 ? mb1 : mb2);
    const float4* wr = (const float4*)(mw + (size_t)j * 1024);
    float4 wv[4];
#pragma unroll
    for (int t = 0; t < 4; t++) wv[t] = wr[lane + t * 64];
    float s[8];
#pragma unroll
    for (int b = 0; b < 8; b++) {
        const float4* c = (const float4*)(cond + b * 1024);
        float a = 0.f;
#pragma unroll
        for (int t = 0; t < 4; t++) {
            float4 cv = c[lane + t * 64];
            a += cv.x * wv[t].x + cv.y * wv[t].y + cv.z * wv[t].z + cv.w * wv[t].w;
        }
#pragma unroll
        for (int o = 32; o > 0; o >>= 1) a += __shfl_xor(a, o, 64);
        s[b] = a;
    }
    if (lane == 0) {
        float base = mb[j];
#pragma unroll
        for (int b = 0; b < 8; b++) mod3[(size_t)p * 24576 + b * 3072 + j] = s[b] + base;
    }
}

// ---------------------------------------------------------------------------
// AdaRMS: bf16 out = x*rsqrt(mean(x^2)+eps)*w*(1+scale)+shift
__global__ __launch_bounds__(256) void adarms_kernel(
    const float* __restrict__ Xf, const float* __restrict__ w,
    const float* __restrict__ mod, u16* __restrict__ Out) {
    __shared__ float red[4];
    const int row = blockIdx.x, tid = threadIdx.x;
    const int bidx = row >> 9;
    const float* x = Xf + (size_t)row * 1024;
    float4 v = *(const float4*)(x + tid * 4);
    float s = v.x * v.x + v.y * v.y + v.z * v.z + v.w * v.w;
#pragma unroll
    for (int o = 32; o > 0; o >>= 1) s += __shfl_xor(s, o, 64);
    if ((tid & 63) == 0) red[tid >> 6] = s;
    __syncthreads();
    float tot = red[0] + red[1] + red[2] + red[3];
    float norm = 1.0f / sqrtf(tot * (1.f / 1024.f) + 1e-6f);
    const float* mo = mod + (size_t)bidx * 3072;
    int d = tid * 4;
    float4 wv = *(const float4*)(w + d);
    const float xv[4] = {v.x, v.y, v.z, v.w};
    const float wa[4] = {wv.x, wv.y, wv.z, wv.w};
    u16 o4[4];
#pragma unroll
    for (int t = 0; t < 4; t++) {
        float sc = mo[d + t], sh = mo[1024 + d + t];
        o4[t] = f2b(xv[t] * norm * wa[t] * (1.f + sc) + sh);
    }
    *(ushort4*)(Out + (size_t)row * 1024 + d) = make_ushort4(o4[0], o4[1], o4[2], o4[3]);
}

// ---------------------------------------------------------------------------
// Staging 128 rows x 32 k into LDS as bf16 (128^2 GEMM).
template <typename T>
__device__ __forceinline__ void stage_tile(const T* __restrict__ G, int ldg, int row0,
                                           int k0, u16* lds, int tid) {
    if constexpr (sizeof(T) == 2) {
        const int wave = tid >> 6, lane = tid & 63;
        const int r4 = lane >> 2, c8 = (lane & 3) * 8;
#pragma unroll
        for (int i = 0; i < 2; i++) {
            int row = wave * 32 + i * 16;
            __builtin_amdgcn_global_load_lds(
                (__attribute__((address_space(1))) void*)((const u16*)G + (size_t)(row0 + row + r4) * ldg + k0 + c8),
                (__attribute__((address_space(3))) void*)(&lds[row * 32]), 16, 0, 0);
        }
    } else {
        const int row = tid >> 1, col = (tid & 1) * 16;
        const float* src = (const float*)G + (size_t)(row0 + row) * ldg + k0 + col;
        float4 f0 = *(const float4*)(src);
        float4 f1 = *(const float4*)(src + 4);
        float4 f2 = *(const float4*)(src + 8);
        float4 f3 = *(const float4*)(src + 12);
        ushort4* dst = (ushort4*)(&lds[row * 32 + col]);
        dst[0] = make_ushort4(f2b(f0.x), f2b(f0.y), f2b(f0.z), f2b(f0.w));
        dst[1] = make_ushort4(f2b(f1.x), f2b(f1.y), f2b(f1.z), f2b(f1.w));
        dst[2] = make_ushort4(f2b(f2.x), f2b(f2.y), f2b(f2.z), f2b(f2.w));
        dst[3] = make_ushort4(f2b(f3.x), f2b(f3.y), f2b(f3.z), f2b(f3.w));
    }
}

// ---------------------------------------------------------------------------
// 128x128 GEMM (N=1024 shapes + fp32 fallback). C = A @ Bw^T.
template <typename TA, typename TB, int MODE>
__global__ __launch_bounds__(256) void gemm_bt(
    const TA* __restrict__ A, const TB* __restrict__ Bw,
    u16* __restrict__ Cb, float* __restrict__ Cf,
    float* __restrict__ Xf, const float* __restrict__ mod,
    int M, int N, int K, int ldc, int coff) {
    __shared__ u16 As[128 * 32];
    __shared__ u16 Bs[128 * 32];
    const int tid = threadIdx.x;
    const int wave = tid >> 6, lane = tid & 63;
    const int gx = gridDim.x, nwg = gx * gridDim.y;
    int bid = blockIdx.y * gx + blockIdx.x;
    bid = (bid & 7) * (nwg >> 3) + (bid >> 3);
    const int m0 = (bid / gx) * 128, n0 = (bid % gx) * 128;
    const int wm = (wave >> 1) * 64, wn = (wave & 1) * 64;
    const int kq = lane >> 4, rr = lane & 15;

    v4f acc[4][4];
#pragma unroll
    for (int i = 0; i < 4; i++)
#pragma unroll
        for (int j = 0; j < 4; j++) acc[i][j] = (v4f){0.f, 0.f, 0.f, 0.f};

    for (int k0 = 0; k0 < K; k0 += 32) {
        __syncthreads();
        stage_tile<TA>(A, K, m0, k0, As, tid);
        stage_tile<TB>(Bw, K, n0, k0, Bs, tid);
        __syncthreads();
        v8bf a[4], b[4];
#pragma unroll
        for (int i = 0; i < 4; i++) a[i] = *(const v8bf*)(&As[(wm + i * 16 + rr) * 32 + kq * 8]);
#pragma unroll
        for (int j = 0; j < 4; j++) b[j] = *(const v8bf*)(&Bs[(wn + j * 16 + rr) * 32 + kq * 8]);
#pragma unroll
        for (int i = 0; i < 4; i++)
#pragma unroll
            for (int j = 0; j < 4; j++)
                acc[i][j] = __builtin_amdgcn_mfma_f32_16x16x32_bf16(a[i], b[j], acc[i][j], 0, 0, 0);
    }

    const int quad = lane >> 4, cl = lane & 15;
#pragma unroll
    for (int i = 0; i < 4; i++)
#pragma unroll
        for (int j = 0; j < 4; j++)
#pragma unroll
            for (int r = 0; r < 4; r++) {
                int row = m0 + wm + i * 16 + quad * 4 + r;
                int col = n0 + wn + j * 16 + cl;
                size_t idx = (size_t)row * ldc + coff + col;
                float v = acc[i][j][r];
                if constexpr (MODE == 0) {
                    Cb[idx] = f2b(v);
                } else if constexpr (MODE == 1) {
                    float g = mod[(row >> 9) * 3072 + 2048 + col];
                    Xf[(size_t)row * 1024 + col] += g * v;
                } else if constexpr (MODE == 2) {
                    float gv = b2f(Cb[idx]);
                    float s = gv / (1.f + __expf(-gv));
                    Cb[idx] = f2b(s * v);
                } else {
                    float g = mod[(row >> 9) * 3072 + 2048 + col];
                    Cf[idx] = Xf[(size_t)row * 1024 + col] + g * v;
                }
            }
}

// ---------------------------------------------------------------------------
// 256x256 / BK=64 8-wave GEMM — round-2 VERIFIED 4-phase schedule (2 barriers
// per phase, counted vmcnt(4), setprio around MFMA, XOR-swizzled LDS staged
// via pre-swizzled global source).  Changes vs round 2: column-major-per-XCD
// tile decode (B panel stays L2-resident per XCD) and MODE 5 SwiGLU epilogue.
__device__ __forceinline__ void stage256(const u16* __restrict__ G, int ldg,
                                         int rowbase, int kcol, u16* lds,
                                         int w, int lane) {
    const int csrc = (lane & 7) ^ (lane >> 3);
    const int rof = csrc >> 2, kof = (csrc & 3) * 8;
#pragma unroll
    for (int q = 0; q < 2; q++) {
        int s = q * 8 + w;                 // 1KB slot: superrows 8s..8s+7
        int sr = s * 8 + (lane >> 3);
        __builtin_amdgcn_global_load_lds(
            (__attribute__((address_space(1))) void*)(G + (size_t)(rowbase + sr * 2 + rof) * ldg + kcol + kof),
            (__attribute__((address_space(3))) void*)(lds + s * 512), 16, 0, 0);
    }
}

__device__ __forceinline__ v8bf frag256(const u16* lds, int r, int kq) {
    int sr = r >> 1;
    int cp = (((r & 1) << 2) | kq) ^ (sr & 7);
    return *(const v8bf*)(lds + sr * 64 + cp * 8);
}

template <int MODE>  // 0: Cb=bf16(acc); 5: interleaved gate/up SwiGLU epilogue
__global__ __launch_bounds__(512, 2) void gemm256(
    const u16* __restrict__ A, const u16* __restrict__ Bw,
    u16* __restrict__ Cb, int K, int ldc, int coff) {
    __shared__ u16 As[2][2][8192];   // [buf][khalf][128 superrows * 64]
    __shared__ u16 Bs[2][2][8192];
    const int tid = threadIdx.x, w = tid >> 6, lane = tid & 63;
    const int gx = gridDim.x, gy = gridDim.y, nwg = gx * gy;
    int bid = blockIdx.y * gx + blockIdx.x;
    bid = (bid & 7) * (nwg >> 3) + (bid >> 3);      // T1 (nwg % 8 == 0)
    // column-major decode: consecutive bids walk M within a fixed N-panel
    const int m0 = (bid % gy) * 256, n0 = (bid / gy) * 256;
    const int wm = w >> 2, wn = w & 3;              // 2 x 4 wave grid
    const int rr = lane & 15, kq = lane >> 4;

    v4f acc[8][4];
#pragma unroll
    for (int i = 0; i < 8; i++)
#pragma unroll
        for (int j = 0; j < 4; j++) acc[i][j] = (v4f){0.f, 0.f, 0.f, 0.f};

    const int nt = K >> 6;
    // prologue: stage tile 0 (units: A-k0, B-k0, A-k1, B-k1)
    stage256(A, K, m0, 0, &As[0][0][0], w, lane);
    stage256(Bw, K, n0, 0, &Bs[0][0][0], w, lane);
    stage256(A, K, m0, 32, &As[0][1][0], w, lane);
    stage256(Bw, K, n0, 32, &Bs[0][1][0], w, lane);
    asm volatile("s_waitcnt vmcnt(4)" ::: "memory");  // k-half 0 resident
    __builtin_amdgcn_s_barrier();

    for (int t = 0; t < nt; ++t) {
        const int buf = t & 1;
        const bool st = (t + 1 < nt);
        const int k1 = (t + 1) << 6;
        const u16* A0 = &As[buf][0][0];
        const u16* B0 = &Bs[buf][0][0];
        const u16* A1 = &As[buf][1][0];
        const u16* B1 = &Bs[buf][1][0];
        u16* nA0 = &As[buf ^ 1][0][0];
        u16* nB0 = &Bs[buf ^ 1][0][0];
        u16* nA1 = &As[buf ^ 1][1][0];
        u16* nB1 = &Bs[buf ^ 1][1][0];
        v8bf af[4], bf[4];

        // ---- phase 0: khalf 0, mi 0..3 ----
#pragma unroll
        for (int j = 0; j < 4; j++) bf[j] = frag256(B0, wn * 64 + j * 16 + rr, kq);
#pragma unroll
        for (int i = 0; i < 4; i++) af[i] = frag256(A0, wm * 128 + i * 16 + rr, kq);
        if (st) stage256(A, K, m0, k1, nA0, w, lane);
        __builtin_amdgcn_s_barrier();
        asm volatile("s_waitcnt lgkmcnt(0)" ::: "memory");
        __builtin_amdgcn_sched_barrier(0);
        __builtin_amdgcn_s_setprio(1);
#pragma unroll
        for (int i = 0; i < 4; i++)
#pragma unroll
            for (int j = 0; j < 4; j++)
                acc[i][j] = __builtin_amdgcn_mfma_f32_16x16x32_bf16(af[i], bf[j], acc[i][j], 0, 0, 0);
        __builtin_amdgcn_s_setprio(0);
        __builtin_amdgcn_s_barrier();

        // ---- phase 1: khalf 0, mi 4..7 (reuses bf) ----
#pragma unroll
        for (int i = 0; i < 4; i++) af[i] = frag256(A0, wm * 128 + 64 + i * 16 + rr, kq);
        if (st) {
            stage256(Bw, K, n0, k1, nB0, w, lane);
            asm volatile("s_waitcnt vmcnt(4)" ::: "memory");  // this tile's khalf 1 resident
        } else {
            asm volatile("s_waitcnt vmcnt(0)" ::: "memory");
        }
        __builtin_amdgcn_s_barrier();
        asm volatile("s_waitcnt lgkmcnt(0)" ::: "memory");
        __builtin_amdgcn_sched_barrier(0);
        __builtin_amdgcn_s_setprio(1);
#pragma unroll
        for (int i = 0; i < 4; i++)
#pragma unroll
            for (int j = 0; j < 4; j++)
                acc[4 + i][j] = __builtin_amdgcn_mfma_f32_16x16x32_bf16(af[i], bf[j], acc[4 + i][j], 0, 0, 0);
        __builtin_amdgcn_s_setprio(0);
        __builtin_amdgcn_s_barrier();

        // ---- phase 2: khalf 1, mi 0..3 ----
#pragma unroll
        for (int j = 0; j < 4; j++) bf[j] = frag256(B1, wn * 64 + j * 16 + rr, kq);
#pragma unroll
        for (int i = 0; i < 4; i++) af[i] = frag256(A1, wm * 128 + i * 16 + rr, kq);
        if (st) stage256(A, K, m0, k1 + 32, nA1, w, lane);
        __builtin_amdgcn_s_barrier();
        asm volatile("s_waitcnt lgkmcnt(0)" ::: "memory");
        __builtin_amdgcn_sched_barrier(0);
        __builtin_amdgcn_s_setprio(1);
#pragma unroll
        for (int i = 0; i < 4; i++)
#pragma unroll
            for (int j = 0; j < 4; j++)
                acc[i][j] = __builtin_amdgcn_mfma_f32_16x16x32_bf16(af[i], bf[j], acc[i][j], 0, 0, 0);
        __builtin_amdgcn_s_setprio(0);
        __builtin_amdgcn_s_barrier();

        // ---- phase 3: khalf 1, mi 4..7 ----
#pragma unroll
        for (int i = 0; i < 4; i++) af[i] = frag256(A1, wm * 128 + 64 + i * 16 + rr, kq);
        if (st) {
            stage256(Bw, K, n0, k1 + 32, nB1, w, lane);
            asm volatile("s_waitcnt vmcnt(4)" ::: "memory");  // next tile's khalf 0 resident
        }
        __builtin_amdgcn_s_barrier();
        asm volatile("s_waitcnt lgkmcnt(0)" ::: "memory");
        __builtin_amdgcn_sched_barrier(0);
        __builtin_amdgcn_s_setprio(1);
#pragma unroll
        for (int i = 0; i < 4; i++)
#pragma unroll
            for (int j = 0; j < 4; j++)
                acc[4 + i][j] = __builtin_amdgcn_mfma_f32_16x16x32_bf16(af[i], bf[j], acc[4 + i][j], 0, 0, 0);
        __builtin_amdgcn_s_setprio(0);
        __builtin_amdgcn_s_barrier();
    }

    // ---- epilogue ----
    const int quad = lane >> 4, cl = lane & 15;
#pragma unroll
    for (int i = 0; i < 8; i++)
#pragma unroll
        for (int j = 0; j < 4; j++)
#pragma unroll
            for (int r = 0; r < 4; r++) {
                int row = m0 + wm * 128 + i * 16 + quad * 4 + r;
                int col = n0 + wn * 64 + j * 16 + cl;
                float v = acc[i][j][r];
                if constexpr (MODE == 0) {
                    Cb[(size_t)row * ldc + coff + col] = f2b(v);
                } else {
                    float o = __shfl_xor(v, 1, 64);
                    if (!(lane & 1)) {
                        float h = (v / (1.f + __expf(-v))) * o;
                        Cb[(size_t)row * ldc + (col >> 1)] = f2b(h);
                    }
                }
            }
}

// ---------------------------------------------------------------------------
// MFMA flash attention. V is now staged TRANSPOSED into LDS (VsT[d][kv],
// XOR-chunk swizzled like Ks) so the PV A-fragment is one aligned b128 read
// instead of 64 scalar ds_read_u16 per wave per chunk.
#define ATTN_SCL 0.125f
__global__ __launch_bounds__(256) void attn_kernel(
    const u16* __restrict__ Q, int ldq,
    const u16* __restrict__ Kp, const u16* __restrict__ Vp, int ldkv,
    u16* __restrict__ Out, int S) {
    __shared__ u16 Ks[64 * 64];
    __shared__ u16 Qs[64 * 64];
    __shared__ u16 Vt[64 * 64];      // V^T: row=d, col=kv, chunk-swizzled
    __shared__ u16 Ps[4][16 * 72];
    const int tid = threadIdx.x, wave = tid >> 6, lane = tid & 63;
    const int b = blockIdx.z, h = blockIdx.y, q0 = blockIdx.x * 64;
    const int Nq = 512;
    const int rr = lane & 15, quad = lane >> 4;
    const int drow = lane >> 3;
    const int dchunk = (lane & 7) ^ drow;

#pragma unroll
    for (int i = 0; i < 2; i++) {
        int r = wave * 16 + i * 8 + drow;
        __builtin_amdgcn_global_load_lds(
            (__attribute__((address_space(1))) void*)(Q + (size_t)(b * Nq + q0 + r) * ldq + h * 64 + dchunk * 8),
            (__attribute__((address_space(3))) void*)(&Qs[(wave * 16 + i * 8) * 64]), 16, 0, 0);
    }
    __syncthreads();

    v8bf qf[2];
#pragma unroll
    for (int h2 = 0; h2 < 2; h2++)
        qf[h2] = *(const v8bf*)(&Qs[(wave * 16 + rr) * 64 + (((quad + 4 * h2) ^ (rr & 7)) * 8)]);

    v4f Oa[4];
#pragma unroll
    for (int t = 0; t < 4; t++) Oa[t] = (v4f){0.f, 0.f, 0.f, 0.f};
    float m = -3e38f, l = 0.f;

    for (int s0 = 0; s0 < S; s0 += 64) {
        __syncthreads();
#pragma unroll
        for (int i = 0; i < 2; i++) {
            int r = wave * 16 + i * 8 + drow;
            __builtin_amdgcn_global_load_lds(
                (__attribute__((address_space(1))) void*)(Kp + (size_t)(b * S + s0 + r) * ldkv + h * 64 + dchunk * 8),
                (__attribute__((address_space(3))) void*)(&Ks[(wave * 16 + i * 8) * 64]), 16, 0, 0);
        }
        // stage V transposed: thread loads 16 d-elems of one kv row, writes
        // them down column kv of Vt (chunk c of row d lives at (c^(d&7))*8).
        {
            int vr = tid >> 2, c0 = (tid & 3) * 16;
            const u16* src = Vp + (size_t)(b * S + s0 + vr) * ldkv + h * 64 + c0;
            uint4 u0 = *(const uint4*)(src);
            uint4 u1 = *(const uint4*)(src + 8);
            u16 e[16];
            e[0] = (u16)u0.x; e[1] = (u16)(u0.x >> 16);
            e[2] = (u16)u0.y; e[3] = (u16)(u0.y >> 16);
            e[4] = (u16)u0.z; e[5] = (u16)(u0.z >> 16);
            e[6] = (u16)u0.w; e[7] = (u16)(u0.w >> 16);
            e[8]  = (u16)u1.x; e[9]  = (u16)(u1.x >> 16);
            e[10] = (u16)u1.y; e[11] = (u16)(u1.y >> 16);
            e[12] = (u16)u1.z; e[13] = (u16)(u1.z >> 16);
            e[14] = (u16)u1.w; e[15] = (u16)(u1.w >> 16);
            const int kc = vr >> 3, ko = vr & 7;
#pragma unroll
            for (int jj = 0; jj < 16; jj++) {
                int d = c0 + jj;
                Vt[d * 64 + ((kc ^ (d & 7)) * 8) + ko] = e[jj];
            }
        }
        __syncthreads();

        v4f Sf[4];
#pragma unroll
        for (int t = 0; t < 4; t++) Sf[t] = (v4f){0.f, 0.f, 0.f, 0.f};
#pragma unroll
        for (int t = 0; t < 4; t++)
#pragma unroll
            for (int h2 = 0; h2 < 2; h2++) {
                v8bf kf = *(const v8bf*)(&Ks[(16 * t + rr) * 64 + (((quad + 4 * h2) ^ (rr & 7)) * 8)]);
                Sf[t] = __builtin_amdgcn_mfma_f32_16x16x32_bf16(kf, qf[h2], Sf[t], 0, 0, 0);
            }
        float mx = -3e38f;
#pragma unroll
        for (int t = 0; t < 4; t++)
#pragma unroll
            for (int r = 0; r < 4; r++) {
                float v = Sf[t][r] * ATTN_SCL;
                Sf[t][r] = v;
                mx = fmaxf(mx, v);
            }
        mx = fmaxf(mx, __shfl_xor(mx, 16, 64));
        mx = fmaxf(mx, __shfl_xor(mx, 32, 64));
        float mn = fmaxf(m, mx);
        float alpha = __expf(m - mn);
        float su = 0.f;
#pragma unroll
        for (int t = 0; t < 4; t++)
#pragma unroll
            for (int r = 0; r < 4; r++) {
                float p = __expf(Sf[t][r] - mn);
                Sf[t][r] = p;
                su += p;
            }
        su += __shfl_xor(su, 16, 64);
        su += __shfl_xor(su, 32, 64);
        l = l * alpha + su;
        m = mn;
#pragma unroll
        for (int t = 0; t < 4; t++)
#pragma unroll
            for (int r = 0; r < 4; r++) Oa[t][r] *= alpha;
#pragma unroll
        for (int t = 0; t < 4; t++) {
            ushort4 pw = make_ushort4(f2b(Sf[t][0]), f2b(Sf[t][1]), f2b(Sf[t][2]), f2b(Sf[t][3]));
            *(ushort4*)(&Ps[wave][rr * 72 + 16 * t + 4 * quad]) = pw;
        }
        v8bf pf[2];
#pragma unroll
        for (int h2 = 0; h2 < 2; h2++)
            pf[h2] = *(const v8bf*)(&Ps[wave][rr * 72 + quad * 8 + 32 * h2]);
#pragma unroll
        for (int t = 0; t < 4; t++)
#pragma unroll
            for (int h2 = 0; h2 < 2; h2++) {
                v8bf vf = *(const v8bf*)(&Vt[(16 * t + rr) * 64 + (((quad + 4 * h2) ^ (rr & 7)) * 8)]);
                Oa[t] = __builtin_amdgcn_mfma_f32_16x16x32_bf16(vf, pf[h2], Oa[t], 0, 0, 0);
            }
    }
    float inv = 1.f / l;
#pragma unroll
    for (int t = 0; t < 4; t++) {
        ushort4 ow = make_ushort4(f2b(Oa[t][0] * inv), f2b(Oa[t][1] * inv),
                                  f2b(Oa[t][2] * inv), f2b(Oa[t][3] * inv));
        *(ushort4*)(&Ps[wave][rr * 72 + 16 * t + 4 * quad]) = ow;
    }
#pragma unroll
    for (int j = 0; j < 2; j++) {
        int idx = j * 64 + lane;
        int ql = idx >> 3, c = (idx & 7) * 8;
        uint4 u = *(const uint4*)(&Ps[wave][ql * 72 + c]);
        *(uint4*)(Out + (size_t)(b * Nq + q0 + wave * 16 + ql) * 1024 + h * 64 + c) = u;
    }
}

// ---------------------------------------------------------------------------
extern "C" void kernel_launch(void* const* d_in, const int* in_sizes, int n_in,
                              void* d_out, int out_size, void* d_ws, size_t ws_size,
                              hipStream_t stream) {
    (void)in_sizes; (void)n_in; (void)out_size;
    const float* x    = (const float*)d_in[0];
    const float* ctx  = (const float*)d_in[1];
    const float* cond = (const float*)d_in[2];
    const float* n1w = (const float*)d_in[3];  const float* n1mw = (const float*)d_in[4];  const float* n1mb = (const float*)d_in[5];
    const float* n2w = (const float*)d_in[6];  const float* n2mw = (const float*)d_in[7];  const float* n2mb = (const float*)d_in[8];
    const float* n3w = (const float*)d_in[9];  const float* n3mw = (const float*)d_in[10]; const float* n3mb = (const float*)d_in[11];
    const float* saq = (const float*)d_in[12]; const float* sak = (const float*)d_in[13];
    const float* sav = (const float*)d_in[14]; const float* sao = (const float*)d_in[15];
    const float* caq = (const float*)d_in[16]; const float* cak = (const float*)d_in[17];
    const float* cav = (const float*)d_in[18]; const float* cao = (const float*)d_in[19];
    const float* ffg = (const float*)d_in[20]; const float* ffu = (const float*)d_in[21];
    const float* ffd = (const float*)d_in[22];
    float* out = (float*)d_out;

    char* ws = (char*)d_ws;
    size_t off = 0;
    auto alloc = [&](size_t bytes) { void* p = ws + off; off += (bytes + 255) & ~(size_t)255; return p; };
    float* xf   = (float*)alloc((size_t)4194304 * 4);
    u16* normed = (u16*)alloc((size_t)4194304 * 2);
    u16* qkv    = (u16*)alloc((size_t)12582912 * 2);
    u16* kvb    = (u16*)alloc((size_t)33554432 * 2);
    u16* obuf   = (u16*)alloc((size_t)4194304 * 2);
    float* mod3 = (float*)alloc((size_t)73728 * 4);
    const size_t MEG = 1048576;
    u16* ctxb = (u16*)alloc((size_t)33554432 * 2);
    u16* wb   = (u16*)alloc((size_t)22 * MEG * 2);
    u16* saq_b = wb;            u16* sak_b = wb + 1 * MEG;  u16* sav_b = wb + 2 * MEG;
    u16* sao_b = wb + 3 * MEG;  u16* caq_b = wb + 4 * MEG;
    u16* cakv_b = wb + 5 * MEG;
    u16* cak_b = wb + 5 * MEG;  u16* cav_b = wb + 7 * MEG;
    u16* cao_b = wb + 9 * MEG;
    u16* ffgu_b = wb + 10 * MEG;   // interleaved gate/up [8192][1024]
    u16* ffd_b  = wb + 18 * MEG;
    const bool CVT = (ws_size >= off);

    hipMemcpyAsync(xf, x, (size_t)4194304 * 4, hipMemcpyDeviceToDevice, stream);
    mod_kernel<<<2304, 256, 0, stream>>>(cond, n1mw, n1mb, n2mw, n2mb, n3mw, n3mb, mod3);

    if (CVT) {
        cvt4_kernel<<<dim3(512, 4), 256, 0, stream>>>(
            saq, saq_b, (int)MEG, sak, sak_b, (int)MEG,
            sav, sav_b, (int)MEG, sao, sao_b, (int)MEG);
        cvt4_kernel<<<dim3(1024, 4), 256, 0, stream>>>(
            cak, cak_b, (int)(2 * MEG), cav, cav_b, (int)(2 * MEG),
            caq, caq_b, (int)MEG, cao, cao_b, (int)MEG);
        cvt_ilv_kernel<<<dim3(2048, 2), 256, 0, stream>>>(ffg, ffu, ffgu_b);
        cvt4_kernel<<<dim3(16384, 2), 256, 0, stream>>>(
            ctx, ctxb, 33554432, ffd, ffd_b, (int)(4 * MEG),
            nullptr, nullptr, 0, nullptr, nullptr, 0);

        // ---- self-attention ----
        adarms_kernel<<<4096, 256, 0, stream>>>(xf, n1w, mod3, normed);
        gemm256<0><<<dim3(12, 16), 512, 0, stream>>>(normed, saq_b, qkv, 1024, 3072, 0);
        attn_kernel<<<dim3(8, 16, 8), 256, 0, stream>>>(qkv, 3072, qkv + 1024, qkv + 2048, 3072, obuf, 512);
        gemm_bt<u16, u16, 1><<<dim3(8, 32), 256, 0, stream>>>(obuf, sao_b, nullptr, nullptr, xf, mod3, 4096, 1024, 1024, 1024, 0);

        // ---- cross-attention ----
        adarms_kernel<<<4096, 256, 0, stream>>>(xf, n2w, mod3 + 24576, normed);
        gemm_bt<u16, u16, 0><<<dim3(8, 32), 256, 0, stream>>>(normed, caq_b, qkv, nullptr, nullptr, nullptr, 4096, 1024, 1024, 1024, 0);
        gemm256<0><<<dim3(8, 64), 512, 0, stream>>>(ctxb, cakv_b, kvb, 2048, 2048, 0);
        attn_kernel<<<dim3(8, 16, 8), 256, 0, stream>>>(qkv, 1024, kvb, kvb + 1024, 2048, obuf, 2048);
        gemm_bt<u16, u16, 1><<<dim3(8, 32), 256, 0, stream>>>(obuf, cao_b, nullptr, nullptr, xf, mod3 + 24576, 4096, 1024, 1024, 1024, 0);

        // ---- SwiGLU MLP: one N=8192 GEMM with fused silu-mul epilogue ----
        adarms_kernel<<<4096, 256, 0, stream>>>(xf, n3w, mod3 + 49152, normed);
        gemm256<5><<<dim3(32, 16), 512, 0, stream>>>(normed, ffgu_b, kvb, 1024, 4096, 0);
        gemm_bt<u16, u16, 3><<<dim3(8, 32), 256, 0, stream>>>(kvb, ffd_b, nullptr, out, xf, mod3 + 49152, 4096, 1024, 4096, 1024, 0);
    } else {
        // ---- fallback: fp32-staging path ----
        adarms_kernel<<<4096, 256, 0, stream>>>(xf, n1w, mod3, normed);
        gemm_bt<u16, float, 0><<<dim3(8, 32), 256, 0, stream>>>(normed, saq, qkv, nullptr, nullptr, nullptr, 4096, 1024, 1024, 3072, 0);
        gemm_bt<u16, float, 0><<<dim3(8, 32), 256, 0, stream>>>(normed, sak, qkv, nullptr, nullptr, nullptr, 4096, 1024, 1024, 3072, 1024);
        gemm_bt<u16, float, 0><<<dim3(8, 32), 256, 0, stream>>>(normed, sav, qkv, nullptr, nullptr, nullptr, 4096, 1024, 1024, 3072, 2048);
        attn_kernel<<<dim3(8, 16, 8), 256, 0, stream>>>(qkv, 3072, qkv + 1024, qkv + 2048, 3072, obuf, 512);
        gemm_bt<u16, float, 1><<<dim3(8, 32), 256, 0, stream>>>(obuf, sao, nullptr, nullptr, xf, mod3, 4096, 1024, 1024, 1024, 0);

        adarms_kernel<<<4096, 256, 0, stream>>>(xf, n2w, mod3 + 24576, normed);
        gemm_bt<u16, float, 0><<<dim3(8, 32), 256, 0, stream>>>(normed, caq, qkv, nullptr, nullptr, nullptr, 4096, 1024, 1024, 1024, 0);
        gemm_bt<float, float, 0><<<dim3(8, 128), 256, 0, stream>>>(ctx, cak, kvb, nullptr, nullptr, nullptr, 16384, 1024, 2048, 2048, 0);
        gemm_bt<float, float, 0><<<dim3(8, 128), 256, 0, stream>>>(ctx, cav, kvb, nullptr, nullptr, nullptr, 16384, 1024, 2048, 2048, 1024);
        attn_kernel<<<dim3(8, 16, 8), 256, 0, stream>>>(qkv, 1024, kvb, kvb + 1024, 2048, obuf, 2048);
        gemm_bt<u16, float, 1><<<dim3(8, 32), 256, 0, stream>>>(obuf, cao, nullptr, nullptr, xf, mod3 + 24576, 4096, 1024, 1024, 1024, 0);

        adarms_kernel<<<4096, 256, 0, stream>>>(xf, n3w, mod3 + 49152, normed);
        gemm_bt<u16, float, 0><<<dim3(32, 32), 256, 0, stream>>>(normed, ffg, kvb, nullptr, nullptr, nullptr, 4096, 4096, 1024, 4096, 0);
        gemm_bt<u16, float, 2><<<dim3(32, 32), 256, 0, stream>>>(normed, ffu, kvb, nullptr, nullptr, nullptr, 4096, 4096, 1024, 4096, 0);
        gemm_bt<u16, float, 3><<<dim3(8, 32), 256, 0, stream>>>(kvb, ffd, nullptr, out, xf, mod3 + 49152, 4096, 1024, 4096, 1024, 0);
    }
}